// Round 1
// baseline (8688.597 us; speedup 1.0000x reference)
//
#include <hip/hip_runtime.h>
#include <hip/hip_bf16.h>
#include <math.h>

#define N_NODES 100000
#define HEADS 8
#define NEG_SLOPE 0.2f

// ---------------------------------------------------------------- CSR build
__global__ void k_initdeg(int* __restrict__ deg, int N) {
    int i = blockIdx.x * 256 + threadIdx.x;
    if (i < N) deg[i] = 1;  // self-loop
}

__global__ void k_count(const int* __restrict__ ei, int* __restrict__ deg, int E) {
    int i = blockIdx.x * 256 + threadIdx.x;
    if (i < E) atomicAdd(&deg[ei[E + i]], 1);  // dst row
}

__global__ void k_scan_block(const int* __restrict__ deg, int* __restrict__ offs,
                             int* __restrict__ bsum, int N) {
    __shared__ int lds[256];
    int tid = threadIdx.x;
    int base = blockIdx.x * 1024 + tid * 4;
    int v0 = (base + 0 < N) ? deg[base + 0] : 0;
    int v1 = (base + 1 < N) ? deg[base + 1] : 0;
    int v2 = (base + 2 < N) ? deg[base + 2] : 0;
    int v3 = (base + 3 < N) ? deg[base + 3] : 0;
    int t01 = v0 + v1;
    int tot = t01 + v2 + v3;
    lds[tid] = tot;
    __syncthreads();
    for (int off = 1; off < 256; off <<= 1) {
        int x = 0;
        if (tid >= off) x = lds[tid - off];
        __syncthreads();
        lds[tid] += x;
        __syncthreads();
    }
    int ex = lds[tid] - tot;
    if (tid == 255) bsum[blockIdx.x] = lds[255];
    if (base + 0 < N) offs[base + 0] = ex;
    if (base + 1 < N) offs[base + 1] = ex + v0;
    if (base + 2 < N) offs[base + 2] = ex + t01;
    if (base + 3 < N) offs[base + 3] = ex + t01 + v2;
}

__global__ void k_scan_top(int* __restrict__ bsum, int nb) {
    if (threadIdx.x == 0 && blockIdx.x == 0) {
        int run = 0;
        for (int b = 0; b < nb; ++b) { int t = bsum[b]; bsum[b] = run; run += t; }
        bsum[nb] = run;
    }
}

__global__ void k_scan_add(int* __restrict__ offs, const int* __restrict__ bsum, int N) {
    int i = blockIdx.x * 256 + threadIdx.x;
    if (i < N) offs[i] += bsum[i >> 10];
    if (i == 0) offs[N] = bsum[(N + 1023) >> 10];
}

__global__ void k_initcur(int* __restrict__ cur, const int* __restrict__ offs, int N) {
    int i = blockIdx.x * 256 + threadIdx.x;
    if (i < N) cur[i] = offs[i];
}

__global__ void k_scatter(const int* __restrict__ ei, int* __restrict__ cur,
                          int* __restrict__ csr, int E, int ET) {
    int i = blockIdx.x * 256 + threadIdx.x;
    if (i >= ET) return;
    int s, d;
    if (i < E) { s = ei[i]; d = ei[E + i]; }
    else       { s = d = i - E; }
    int pos = atomicAdd(&cur[d], 1);
    csr[pos] = s;
}

// ---------------------------------------------------------------- dense GEMM: out[N,M] = X[N,K] @ W[M,K]^T + b1 + b2
template <int RPT>
__global__ void k_gemm(const float* __restrict__ X, const float* __restrict__ W,
                       const float* __restrict__ bias1, const float* __restrict__ bias2,
                       float* __restrict__ out, int N, int K, int M) {
    extern __shared__ float lds[];
    const int Kp = K + 4;
    float* sW = lds;            // M * Kp
    float* sX = lds + M * Kp;   // rows * Kp
    int tx = threadIdx.x, ty = threadIdx.y;
    int nthr = blockDim.x * blockDim.y;
    int tid = ty * blockDim.x + tx;
    int rows = blockDim.y * RPT;
    int r0 = blockIdx.x * rows;

    for (int i = tid * 4; i < M * K; i += nthr * 4) {
        int m = i / K, k = i % K;
        float4 v = *(const float4*)&W[i];
        *(float4*)&sW[m * Kp + k] = v;
    }
    for (int i = tid * 4; i < rows * K; i += nthr * 4) {
        int rl = i / K, k = i % K;
        int gr = r0 + rl;
        float4 v = make_float4(0.f, 0.f, 0.f, 0.f);
        if (gr < N) v = *(const float4*)&X[(size_t)gr * K + k];
        *(float4*)&sX[rl * Kp + k] = v;
    }
    __syncthreads();

    float b = (bias1 ? bias1[tx] : 0.f) + (bias2 ? bias2[tx] : 0.f);
    float acc[RPT];
#pragma unroll
    for (int r = 0; r < RPT; ++r) acc[r] = b;

    for (int k = 0; k < K; k += 4) {
        float4 w4 = *(const float4*)&sW[tx * Kp + k];
#pragma unroll
        for (int r = 0; r < RPT; ++r) {
            float4 x4 = *(const float4*)&sX[(ty * RPT + r) * Kp + k];
            acc[r] += w4.x * x4.x + w4.y * x4.y + w4.z * x4.z + w4.w * x4.w;
        }
    }
#pragma unroll
    for (int r = 0; r < RPT; ++r) {
        int gr = r0 + ty * RPT + r;
        if (gr < N) out[(size_t)gr * M + tx] = acc[r];
    }
}

// ---------------------------------------------------------------- attention logits for layers 0/1 (C=8)
__global__ void k_al(const float* __restrict__ H, const float* __restrict__ as_w,
                     const float* __restrict__ ad_w, float* __restrict__ AL, int N) {
    int t = blockIdx.x * 256 + threadIdx.x;
    int n = t >> 4;
    if (n >= N) return;
    int j = t & 15;
    int hd = j & 7;
    const float* a = (j < 8 ? as_w : ad_w) + hd * 8;
    const float* hp = H + (size_t)n * 64 + hd * 8;
    float sum = 0.f;
#pragma unroll
    for (int c = 0; c < 8; ++c) sum += a[c] * hp[c];
    AL[t] = sum;
}

// wt[j,k] = sum_c a[j][c] * W2[(hd*40+c)*64 + k]   (j<8: a_src, j>=8: a_dst)
__global__ void k_wt(const float* __restrict__ W2, const float* __restrict__ as2,
                     const float* __restrict__ ad2, float* __restrict__ wt) {
    int t = blockIdx.x * 256 + threadIdx.x;
    if (t >= 1024) return;
    int j = t >> 6, k = t & 63;
    int hd = j & 7;
    const float* a = (j < 8 ? as2 : ad2) + hd * 40;
    float sum = 0.f;
    for (int c = 0; c < 40; ++c) sum += a[c] * W2[(size_t)(hd * 40 + c) * 64 + k];
    wt[j * 64 + k] = sum;
}

// ---------------------------------------------------------------- layers 0/1: per-node online softmax + aggregate + skip + ELU (in place on S)
__global__ __launch_bounds__(256) void k_aggregate(
    const float* __restrict__ H, const float* __restrict__ AL,
    const int* __restrict__ offs, const int* __restrict__ csr,
    float* __restrict__ S, int N) {
    int wave = threadIdx.x >> 6;
    int lane = threadIdx.x & 63;
    int n = blockIdx.x * 4 + wave;
    if (n >= N) return;
    int hd = lane >> 3;
    int off = offs[n], deg = offs[n + 1] - off;
    float ald = AL[(size_t)n * 16 + 8 + hd];

    float m = -INFINITY, s = 0.f;
    for (int b0 = 0; b0 < deg; b0 += 64) {
        int cnt = min(deg - b0, 64);
        int msrc = (lane < cnt) ? csr[off + b0 + lane] : 0;
        for (int i = 0; i < cnt; ++i) {
            int src = __shfl(msrc, i);
            float v = AL[(size_t)src * 16 + hd] + ald;
            v = v > 0.f ? v : NEG_SLOPE * v;
            float nm = fmaxf(m, v);
            s = s * __expf(m - nm) + __expf(v - nm);
            m = nm;
        }
    }
    float sinv = 1.0f / (s + 1e-16f);

    float acc = 0.f;
    for (int b0 = 0; b0 < deg; b0 += 64) {
        int cnt = min(deg - b0, 64);
        int msrc = (lane < cnt) ? csr[off + b0 + lane] : 0;
        for (int i = 0; i < cnt; ++i) {
            int src = __shfl(msrc, i);
            float v = AL[(size_t)src * 16 + hd] + ald;
            v = v > 0.f ? v : NEG_SLOPE * v;
            float alpha = __expf(v - m) * sinv;
            acc += alpha * H[(size_t)src * 64 + lane];
        }
    }
    float val = S[(size_t)n * 64 + lane] + acc;
    S[(size_t)n * 64 + lane] = val > 0.f ? val : expm1f(val);
}

// ---------------------------------------------------------------- layer 2: aggregate x in input space per head, project via W2 (LDS), + skip, log_softmax
#define W2S 68
__global__ __launch_bounds__(512) void k_layer2(
    const float* __restrict__ X, const float* __restrict__ AL,
    const float* __restrict__ SK, const float* __restrict__ W2,
    const int* __restrict__ offs, const int* __restrict__ csr,
    float* __restrict__ out, int N) {
    __shared__ float sW2[320 * W2S];   // 87,040 B, row-major padded
    __shared__ float sAgg[16][512];    // 32,768 B: [wave*2+p][hd*64+k]

    int tid = threadIdx.x;
    for (int i = tid; i < 320 * 64; i += 512) {
        int row = i >> 6, k = i & 63;
        sW2[row * W2S + k] = W2[i];
    }
    __syncthreads();

    int wave = tid >> 6, lane = tid & 63;
    int r8 = lane & 7;
    int nbase = blockIdx.x * 16 + wave * 2;

    for (int p = 0; p < 2; ++p) {
        int n = nbase + p;
        float acc[8] = {0.f, 0.f, 0.f, 0.f, 0.f, 0.f, 0.f, 0.f};
        if (n < N) {
            int off = offs[n], deg = offs[n + 1] - off;
            float ald = AL[(size_t)n * 16 + 8 + r8];
            float m = -INFINITY, s = 0.f;
            for (int b0 = 0; b0 < deg; b0 += 64) {
                int cnt = min(deg - b0, 64);
                int msrc = (lane < cnt) ? csr[off + b0 + lane] : 0;
                for (int i = 0; i < cnt; ++i) {
                    int src = __shfl(msrc, i);
                    float v = AL[(size_t)src * 16 + r8] + ald;
                    v = v > 0.f ? v : NEG_SLOPE * v;
                    float nm = fmaxf(m, v);
                    s = s * __expf(m - nm) + __expf(v - nm);
                    m = nm;
                }
            }
            float sinv = 1.0f / (s + 1e-16f);
            for (int b0 = 0; b0 < deg; b0 += 64) {
                int cnt = min(deg - b0, 64);
                int msrc = (lane < cnt) ? csr[off + b0 + lane] : 0;
                for (int i = 0; i < cnt; ++i) {
                    int src = __shfl(msrc, i);
                    float v = AL[(size_t)src * 16 + r8] + ald;
                    v = v > 0.f ? v : NEG_SLOPE * v;
                    float aval = __expf(v - m) * sinv;
                    float xv = X[(size_t)src * 64 + lane];
#pragma unroll
                    for (int r = 0; r < 8; ++r) {
                        float al = __shfl(aval, r);  // lane r holds head r's alpha
                        acc[r] += al * xv;
                    }
                }
            }
        }
#pragma unroll
        for (int r = 0; r < 8; ++r) sAgg[wave * 2 + p][r * 64 + lane] = acc[r];
    }
    // same-wave LDS produce->consume; compiler inserts lgkmcnt waits.
    int cc = lane < 40 ? lane : 39;
    float oA = 0.f, oB = 0.f;
    int sA = wave * 2, sB = wave * 2 + 1;
#pragma unroll
    for (int hd = 0; hd < 8; ++hd) {
        const float* wrow = &sW2[(hd * 40 + cc) * W2S];
        const float* gA = &sAgg[sA][hd * 64];
        const float* gB = &sAgg[sB][hd * 64];
#pragma unroll
        for (int k = 0; k < 64; k += 4) {
            float4 w4 = *(const float4*)&wrow[k];
            float4 a4 = *(const float4*)&gA[k];
            float4 b4 = *(const float4*)&gB[k];
            oA += w4.x * a4.x + w4.y * a4.y + w4.z * a4.z + w4.w * a4.w;
            oB += w4.x * b4.x + w4.y * b4.y + w4.z * b4.z + w4.w * b4.w;
        }
    }
    for (int p = 0; p < 2; ++p) {
        int n = nbase + p;
        if (n >= N) continue;
        float o = (p ? oB : oA) * 0.125f;
        float val = (lane < 40) ? SK[(size_t)n * 40 + lane] + o : -INFINITY;
        float mx = val;
#pragma unroll
        for (int d = 32; d; d >>= 1) mx = fmaxf(mx, __shfl_xor(mx, d));
        float ex = (lane < 40) ? __expf(val - mx) : 0.f;
        float sm = ex;
#pragma unroll
        for (int d = 32; d; d >>= 1) sm += __shfl_xor(sm, d);
        if (lane < 40) out[(size_t)n * 40 + lane] = val - mx - logf(sm);
    }
}

// ---------------------------------------------------------------- launch
extern "C" void kernel_launch(void* const* d_in, const int* in_sizes, int n_in,
                              void* d_out, int out_size, void* d_ws, size_t ws_size,
                              hipStream_t stream) {
    const float* x   = (const float*)d_in[0];
    const int*   ei  = (const int*)d_in[1];
    const float* W0  = (const float*)d_in[2];
    const float* as0 = (const float*)d_in[3];
    const float* ad0 = (const float*)d_in[4];
    const float* b0  = (const float*)d_in[5];
    const float* sW0 = (const float*)d_in[6];
    const float* sb0 = (const float*)d_in[7];
    const float* W1  = (const float*)d_in[8];
    const float* as1 = (const float*)d_in[9];
    const float* ad1 = (const float*)d_in[10];
    const float* b1  = (const float*)d_in[11];
    const float* sW1 = (const float*)d_in[12];
    const float* sb1 = (const float*)d_in[13];
    const float* W2  = (const float*)d_in[14];
    const float* as2 = (const float*)d_in[15];
    const float* ad2 = (const float*)d_in[16];
    const float* b2  = (const float*)d_in[17];
    const float* sW2 = (const float*)d_in[18];
    const float* sb2 = (const float*)d_in[19];
    float* out = (float*)d_out;

    int N = in_sizes[0] / 128;
    int E = in_sizes[1] / 2;
    int ET = E + N;

    char* wsp = (char*)d_ws;
    size_t woff = 0;
    auto A = [&](size_t nbytes) -> void* {
        void* p = wsp + woff;
        woff = (woff + nbytes + 255) & ~(size_t)255;
        return p;
    };
    int* offs  = (int*)A((size_t)(N + 1) * 4);
    int* cur   = (int*)A((size_t)N * 4);
    int* deg   = (int*)A((size_t)N * 4);
    int* bsum  = (int*)A(4096);
    int* csr   = (int*)A((size_t)ET * 4);
    float* wt  = (float*)A(1024 * 4);
    float* AL  = (float*)A((size_t)N * 16 * 4);
    float* H   = (float*)A((size_t)N * 64 * 4);
    float* S   = (float*)A((size_t)N * 64 * 4);
    float* T   = (float*)A((size_t)N * 64 * 4);
    (void)ws_size; (void)n_in; (void)out_size;

    // ---- CSR build (per call; deterministic semantics)
    k_initdeg<<<(N + 255) / 256, 256, 0, stream>>>(deg, N);
    k_count<<<(E + 255) / 256, 256, 0, stream>>>(ei, deg, E);
    int nb = (N + 1023) / 1024;
    k_scan_block<<<nb, 256, 0, stream>>>(deg, offs, bsum, N);
    k_scan_top<<<1, 1, 0, stream>>>(bsum, nb);
    k_scan_add<<<(N + 255) / 256, 256, 0, stream>>>(offs, bsum, N);
    k_initcur<<<(N + 255) / 256, 256, 0, stream>>>(cur, offs, N);
    k_scatter<<<(ET + 255) / 256, 256, 0, stream>>>(ei, cur, csr, E, ET);

    dim3 b64(64, 4);
    dim3 b16(16, 16);
    dim3 b40(40, 6);
    size_t shA = (size_t)(64 * 132 + 32 * 132) * 4;  // K=128, M=64
    size_t shB = (size_t)(64 * 68 + 32 * 68) * 4;    // K=64,  M=64
    size_t shC = (size_t)(16 * 68 + 128 * 68) * 4;   // K=64,  M=16
    size_t shD = (size_t)(40 * 68 + 48 * 68) * 4;    // K=64,  M=40

    // ---- layer 0 (input x [N,128])
    k_gemm<8><<<(N + 31) / 32, b64, shA, stream>>>(x, W0, nullptr, nullptr, H, N, 128, 64);
    k_gemm<8><<<(N + 31) / 32, b64, shA, stream>>>(x, sW0, b0, sb0, S, N, 128, 64);
    k_al<<<(N * 16 + 255) / 256, 256, 0, stream>>>(H, as0, ad0, AL, N);
    k_aggregate<<<(N + 3) / 4, 256, 0, stream>>>(H, AL, offs, csr, S, N);  // S <- elu(S + gat) = x1

    // ---- layer 1 (input S [N,64])
    k_gemm<8><<<(N + 31) / 32, b64, shB, stream>>>(S, W1, nullptr, nullptr, H, N, 64, 64);
    k_gemm<8><<<(N + 31) / 32, b64, shB, stream>>>(S, sW1, b1, sb1, T, N, 64, 64);
    k_al<<<(N * 16 + 255) / 256, 256, 0, stream>>>(H, as1, ad1, AL, N);
    k_aggregate<<<(N + 3) / 4, 256, 0, stream>>>(H, AL, offs, csr, T, N);  // T <- x2

    // ---- layer 2 (input T [N,64])
    k_wt<<<4, 256, 0, stream>>>(W2, as2, ad2, wt);
    k_gemm<8><<<(N + 127) / 128, b16, shC, stream>>>(T, wt, nullptr, nullptr, AL, N, 64, 16);
    k_gemm<8><<<(N + 47) / 48, b40, shD, stream>>>(T, sW2, b2, sb2, S, N, 64, 40);
    k_layer2<<<(N + 15) / 16, 512, 0, stream>>>(T, AL, S, W2, offs, csr, out, N);
}

// Round 2
// 1264.342 us; speedup vs baseline: 6.8720x; 6.8720x over previous
//
#include <hip/hip_runtime.h>
#include <hip/hip_bf16.h>
#include <math.h>

#define HEADS 8
#define NEG_SLOPE 0.2f

// ---------------------------------------------------------------- CSR build
__global__ void k_initdeg(int* __restrict__ deg, int N) {
    int i = blockIdx.x * 256 + threadIdx.x;
    if (i < N) deg[i] = 1;  // self-loop
}

__global__ void k_count(const int* __restrict__ ei, int* __restrict__ deg, int E) {
    int i = blockIdx.x * 256 + threadIdx.x;
    if (i < E) atomicAdd(&deg[ei[E + i]], 1);  // dst row
}

__global__ void k_scan_block(const int* __restrict__ deg, int* __restrict__ offs,
                             int* __restrict__ bsum, int N) {
    __shared__ int lds[256];
    int tid = threadIdx.x;
    int base = blockIdx.x * 1024 + tid * 4;
    int v0 = (base + 0 < N) ? deg[base + 0] : 0;
    int v1 = (base + 1 < N) ? deg[base + 1] : 0;
    int v2 = (base + 2 < N) ? deg[base + 2] : 0;
    int v3 = (base + 3 < N) ? deg[base + 3] : 0;
    int t01 = v0 + v1;
    int tot = t01 + v2 + v3;
    lds[tid] = tot;
    __syncthreads();
    for (int off = 1; off < 256; off <<= 1) {
        int x = 0;
        if (tid >= off) x = lds[tid - off];
        __syncthreads();
        lds[tid] += x;
        __syncthreads();
    }
    int ex = lds[tid] - tot;
    if (tid == 255) bsum[blockIdx.x] = lds[255];
    if (base + 0 < N) offs[base + 0] = ex;
    if (base + 1 < N) offs[base + 1] = ex + v0;
    if (base + 2 < N) offs[base + 2] = ex + t01;
    if (base + 3 < N) offs[base + 3] = ex + t01 + v2;
}

__global__ void k_scan_top(int* __restrict__ bsum, int nb) {
    if (threadIdx.x == 0 && blockIdx.x == 0) {
        int run = 0;
        for (int b = 0; b < nb; ++b) { int t = bsum[b]; bsum[b] = run; run += t; }
        bsum[nb] = run;
    }
}

__global__ void k_scan_add(int* __restrict__ offs, const int* __restrict__ bsum, int N) {
    int i = blockIdx.x * 256 + threadIdx.x;
    if (i < N) offs[i] += bsum[i >> 10];
    if (i == 0) offs[N] = bsum[(N + 1023) >> 10];
}

__global__ void k_initcur(int* __restrict__ cur, const int* __restrict__ offs, int N) {
    int i = blockIdx.x * 256 + threadIdx.x;
    if (i < N) cur[i] = offs[i];
}

__global__ void k_scatter(const int* __restrict__ ei, int* __restrict__ cur,
                          int* __restrict__ csr, int* __restrict__ dstid, int E, int ET) {
    int i = blockIdx.x * 256 + threadIdx.x;
    if (i >= ET) return;
    int s, d;
    if (i < E) { s = ei[i]; d = ei[E + i]; }
    else       { s = d = i - E; }
    int pos = atomicAdd(&cur[d], 1);
    csr[pos] = s;
    dstid[pos] = d;
}

// ---------------------------------------------------------------- dense GEMM: out[N,M] = X[N,K] @ W[M,K]^T + b1 + b2
template <int RPT>
__global__ void k_gemm(const float* __restrict__ X, const float* __restrict__ W,
                       const float* __restrict__ bias1, const float* __restrict__ bias2,
                       float* __restrict__ out, int N, int K, int M) {
    extern __shared__ float lds[];
    const int Kp = K + 4;
    float* sW = lds;            // M * Kp
    float* sX = lds + M * Kp;   // rows * Kp
    int tx = threadIdx.x, ty = threadIdx.y;
    int nthr = blockDim.x * blockDim.y;
    int tid = ty * blockDim.x + tx;
    int rows = blockDim.y * RPT;
    int r0 = blockIdx.x * rows;

    for (int i = tid * 4; i < M * K; i += nthr * 4) {
        int m = i / K, k = i % K;
        float4 v = *(const float4*)&W[i];
        *(float4*)&sW[m * Kp + k] = v;
    }
    for (int i = tid * 4; i < rows * K; i += nthr * 4) {
        int rl = i / K, k = i % K;
        int gr = r0 + rl;
        float4 v = make_float4(0.f, 0.f, 0.f, 0.f);
        if (gr < N) v = *(const float4*)&X[(size_t)gr * K + k];
        *(float4*)&sX[rl * Kp + k] = v;
    }
    __syncthreads();

    float b = (bias1 ? bias1[tx] : 0.f) + (bias2 ? bias2[tx] : 0.f);
    float acc[RPT];
#pragma unroll
    for (int r = 0; r < RPT; ++r) acc[r] = b;

    for (int k = 0; k < K; k += 4) {
        float4 w4 = *(const float4*)&sW[tx * Kp + k];
#pragma unroll
        for (int r = 0; r < RPT; ++r) {
            float4 x4 = *(const float4*)&sX[(ty * RPT + r) * Kp + k];
            acc[r] += w4.x * x4.x + w4.y * x4.y + w4.z * x4.z + w4.w * x4.w;
        }
    }
#pragma unroll
    for (int r = 0; r < RPT; ++r) {
        int gr = r0 + ty * RPT + r;
        if (gr < N) out[(size_t)gr * M + tx] = acc[r];
    }
}

// ---------------------------------------------------------------- attention logits for layers 0/1 (C=8)
__global__ void k_al(const float* __restrict__ H, const float* __restrict__ as_w,
                     const float* __restrict__ ad_w, float* __restrict__ AL, int N) {
    int t = blockIdx.x * 256 + threadIdx.x;
    int n = t >> 4;
    if (n >= N) return;
    int j = t & 15;
    int hd = j & 7;
    const float* a = (j < 8 ? as_w : ad_w) + hd * 8;
    const float* hp = H + (size_t)n * 64 + hd * 8;
    float sum = 0.f;
#pragma unroll
    for (int c = 0; c < 8; ++c) sum += a[c] * hp[c];
    AL[t] = sum;
}

// wt[j,k] = sum_c a[j][c] * W2[(hd*40+c)*64 + k]   (j<8: a_src, j>=8: a_dst)
__global__ void k_wt(const float* __restrict__ W2, const float* __restrict__ as2,
                     const float* __restrict__ ad2, float* __restrict__ wt) {
    int t = blockIdx.x * 256 + threadIdx.x;
    if (t >= 1024) return;
    int j = t >> 6, k = t & 63;
    int hd = j & 7;
    const float* a = (j < 8 ? as2 : ad2) + hd * 40;
    float sum = 0.f;
    for (int c = 0; c < 40; ++c) sum += a[c] * W2[(size_t)(hd * 40 + c) * 64 + k];
    wt[j * 64 + k] = sum;
}

// W2T[hd*64+k][c] = W2[(hd*40+c)*64 + k]   (512 x 40)
__global__ void k_w2t(const float* __restrict__ W2, float* __restrict__ W2T) {
    int t = blockIdx.x * 256 + threadIdx.x;
    if (t >= 512 * 40) return;
    int row = t / 40, c = t % 40;
    W2T[t] = W2[(size_t)((row >> 6) * 40 + c) * 64 + (row & 63)];
}

// ---------------------------------------------------------------- edge logits (edge-parallel, 8 lanes/edge)
__global__ void k_edges(const float* __restrict__ AL, const int* __restrict__ csr,
                        const int* __restrict__ dstid, float* __restrict__ EL, int ET) {
    int t = blockIdx.x * 256 + threadIdx.x;
    int slot = t >> 3;
    if (slot >= ET) return;
    int hd = t & 7;
    int s = csr[slot], d = dstid[slot];
    float v = AL[(size_t)s * 16 + hd] + AL[(size_t)d * 16 + 8 + hd];
    EL[t] = v > 0.f ? v : NEG_SLOPE * v;
}

// ---------------------------------------------------------------- per-node softmax stats, EL -> alpha in place (1 wave/node)
__global__ __launch_bounds__(256) void k_stats(float* __restrict__ EL,
                                               const int* __restrict__ offs, int N) {
    int wid = threadIdx.x >> 6, lane = threadIdx.x & 63;
    int n = blockIdx.x * 4 + wid;
    if (n >= N) return;
    int off = offs[n], deg = offs[n + 1] - off;
    int el = lane >> 3, hd = lane & 7;  // lane = e*8 + hd (coalesced)

    float m = -1e30f, s = 0.f;
    for (int b0 = 0; b0 < deg; b0 += 8) {
        int e = b0 + el;
        if (e < deg) {
            float v = EL[(size_t)(off + e) * 8 + hd];
            float nm = fmaxf(m, v);
            s = s * __expf(m - nm) + __expf(v - nm);
            m = nm;
        }
    }
    // reduce over the 8 e-slots (lanes differing in bits 3,4,5)
#pragma unroll
    for (int d = 8; d <= 32; d <<= 1) {
        float mo = __shfl_xor(m, d), so = __shfl_xor(s, d);
        float nm = fmaxf(m, mo);
        s = s * __expf(m - nm) + so * __expf(mo - nm);
        m = nm;
    }
    float sinv = 1.0f / (s + 1e-16f);
    for (int b0 = 0; b0 < deg; b0 += 8) {
        int e = b0 + el;
        if (e < deg) {
            size_t idx = (size_t)(off + e) * 8 + hd;
            EL[idx] = __expf(EL[idx] - m) * sinv;
        }
    }
}

// ---------------------------------------------------------------- layers 0/1 aggregate: acc += alpha * H[src], + skip, ELU (in place on S)
__global__ __launch_bounds__(256) void k_agg(
    const float* __restrict__ H, const float* __restrict__ ALPHA,
    const int* __restrict__ offs, const int* __restrict__ csr,
    float* __restrict__ S, int N) {
    int wid = threadIdx.x >> 6, lane = threadIdx.x & 63;
    int n = blockIdx.x * 4 + wid;
    if (n >= N) return;
    int off = offs[n], deg = offs[n + 1] - off;
    int hd = lane >> 3;
    float acc = 0.f;
    int e = 0;
    for (; e + 4 <= deg; e += 4) {
        int s0 = csr[off + e + 0], s1 = csr[off + e + 1];
        int s2 = csr[off + e + 2], s3 = csr[off + e + 3];
        float a0 = ALPHA[(size_t)(off + e + 0) * 8 + hd];
        float a1 = ALPHA[(size_t)(off + e + 1) * 8 + hd];
        float a2 = ALPHA[(size_t)(off + e + 2) * 8 + hd];
        float a3 = ALPHA[(size_t)(off + e + 3) * 8 + hd];
        float h0 = H[(size_t)s0 * 64 + lane];
        float h1 = H[(size_t)s1 * 64 + lane];
        float h2 = H[(size_t)s2 * 64 + lane];
        float h3 = H[(size_t)s3 * 64 + lane];
        acc += a0 * h0 + a1 * h1 + a2 * h2 + a3 * h3;
    }
    for (; e < deg; ++e) {
        int s0 = csr[off + e];
        float a0 = ALPHA[(size_t)(off + e) * 8 + hd];
        acc += a0 * H[(size_t)s0 * 64 + lane];
    }
    float val = S[(size_t)n * 64 + lane] + acc;
    S[(size_t)n * 64 + lane] = val > 0.f ? val : expm1f(val);
}

// ---------------------------------------------------------------- layer 2: aggregate in 64-dim input space (8 heads), project via W2T, skip, log_softmax
__global__ __launch_bounds__(512, 4) void k_agg2(
    const float* __restrict__ X, const float* __restrict__ ALPHA,
    const float* __restrict__ SK, const float* __restrict__ W2T,
    const int* __restrict__ offs, const int* __restrict__ csr,
    float* __restrict__ out, int N) {
    __shared__ float agg[8][516];  // per-wave AGG[hd][k], row base 2064 B (16B-aligned)
    int wid = threadIdx.x >> 6, lane = threadIdx.x & 63;
    int n = blockIdx.x * 8 + wid;

    float acc[8] = {0.f, 0.f, 0.f, 0.f, 0.f, 0.f, 0.f, 0.f};
    int off = 0, deg = 0;
    if (n < N) { off = offs[n]; deg = offs[n + 1] - off; }

    int e = 0;
    for (; e + 2 <= deg; e += 2) {
        int s0 = csr[off + e], s1 = csr[off + e + 1];
        float xv0 = X[(size_t)s0 * 64 + lane];
        float xv1 = X[(size_t)s1 * 64 + lane];
        const float* a0 = &ALPHA[(size_t)(off + e) * 8];
        const float* a1 = &ALPHA[(size_t)(off + e + 1) * 8];
#pragma unroll
        for (int r = 0; r < 8; ++r) acc[r] += a0[r] * xv0 + a1[r] * xv1;
    }
    if (e < deg) {
        int s0 = csr[off + e];
        float xv0 = X[(size_t)s0 * 64 + lane];
        const float* a0 = &ALPHA[(size_t)(off + e) * 8];
#pragma unroll
        for (int r = 0; r < 8; ++r) acc[r] += a0[r] * xv0;
    }
#pragma unroll
    for (int r = 0; r < 8; ++r) agg[wid][r * 64 + lane] = acc[r];
    // same-wave LDS produce->consume (no cross-wave sharing; compiler waits lgkmcnt)

    int cc = lane < 40 ? lane : 39;
    float o = 0.f;
    for (int q = 0; q < 128; ++q) {
        float4 g = *(const float4*)&agg[wid][q * 4];
        const float* w = &W2T[(size_t)q * 160 + cc];
        o += g.x * w[0] + g.y * w[40] + g.z * w[80] + g.w * w[120];
    }

    if (n < N) {
        float val = (lane < 40) ? SK[(size_t)n * 40 + lane] + o * 0.125f : -INFINITY;
        float mx = val;
#pragma unroll
        for (int d = 32; d; d >>= 1) mx = fmaxf(mx, __shfl_xor(mx, d));
        float ex = (lane < 40) ? __expf(val - mx) : 0.f;
        float sm = ex;
#pragma unroll
        for (int d = 32; d; d >>= 1) sm += __shfl_xor(sm, d);
        if (lane < 40) out[(size_t)n * 40 + lane] = val - mx - logf(sm);
    }
}

// ---------------------------------------------------------------- launch
extern "C" void kernel_launch(void* const* d_in, const int* in_sizes, int n_in,
                              void* d_out, int out_size, void* d_ws, size_t ws_size,
                              hipStream_t stream) {
    const float* x   = (const float*)d_in[0];
    const int*   ei  = (const int*)d_in[1];
    const float* W0  = (const float*)d_in[2];
    const float* as0 = (const float*)d_in[3];
    const float* ad0 = (const float*)d_in[4];
    const float* b0  = (const float*)d_in[5];
    const float* sW0 = (const float*)d_in[6];
    const float* sb0 = (const float*)d_in[7];
    const float* W1  = (const float*)d_in[8];
    const float* as1 = (const float*)d_in[9];
    const float* ad1 = (const float*)d_in[10];
    const float* b1  = (const float*)d_in[11];
    const float* sW1 = (const float*)d_in[12];
    const float* sb1 = (const float*)d_in[13];
    const float* W2  = (const float*)d_in[14];
    const float* as2 = (const float*)d_in[15];
    const float* ad2 = (const float*)d_in[16];
    const float* b2  = (const float*)d_in[17];
    const float* sW2 = (const float*)d_in[18];
    const float* sb2 = (const float*)d_in[19];
    float* out = (float*)d_out;

    int N = in_sizes[0] / 128;
    int E = in_sizes[1] / 2;
    int ET = E + N;

    char* wsp = (char*)d_ws;
    size_t woff = 0;
    auto A = [&](size_t nbytes) -> void* {
        void* p = wsp + woff;
        woff = (woff + nbytes + 255) & ~(size_t)255;
        return p;
    };
    int* offs   = (int*)A((size_t)(N + 1) * 4);
    int* cur    = (int*)A((size_t)N * 4);
    int* deg    = (int*)A((size_t)N * 4);
    int* bsum   = (int*)A(4096);
    int* csr    = (int*)A((size_t)ET * 4);
    int* dstid  = (int*)A((size_t)ET * 4);
    float* wt   = (float*)A(1024 * 4);
    float* w2t  = (float*)A(512 * 40 * 4);
    float* AL   = (float*)A((size_t)N * 16 * 4);
    float* H    = (float*)A((size_t)N * 64 * 4);
    float* S    = (float*)A((size_t)N * 64 * 4);
    float* T    = (float*)A((size_t)N * 64 * 4);
    float* EL   = (float*)A((size_t)ET * 8 * 4);
    (void)ws_size; (void)n_in; (void)out_size;

    // ---- CSR build
    k_initdeg<<<(N + 255) / 256, 256, 0, stream>>>(deg, N);
    k_count<<<(E + 255) / 256, 256, 0, stream>>>(ei, deg, E);
    int nb = (N + 1023) / 1024;
    k_scan_block<<<nb, 256, 0, stream>>>(deg, offs, bsum, N);
    k_scan_top<<<1, 1, 0, stream>>>(bsum, nb);
    k_scan_add<<<(N + 255) / 256, 256, 0, stream>>>(offs, bsum, N);
    k_initcur<<<(N + 255) / 256, 256, 0, stream>>>(cur, offs, N);
    k_scatter<<<(ET + 255) / 256, 256, 0, stream>>>(ei, cur, csr, dstid, E, ET);

    dim3 b64(64, 4);
    dim3 b16(16, 16);
    dim3 b40(40, 6);
    size_t shA = (size_t)(64 * 132 + 32 * 132) * 4;  // K=128, M=64
    size_t shB = (size_t)(64 * 68 + 32 * 68) * 4;    // K=64,  M=64
    size_t shC = (size_t)(16 * 68 + 128 * 68) * 4;   // K=64,  M=16
    size_t shD = (size_t)(40 * 68 + 48 * 68) * 4;    // K=64,  M=40

    int gE = (ET * 8 + 255) / 256;
    int gN4 = (N + 3) / 4;

    // ---- layer 0 (input x [N,128])
    k_gemm<8><<<(N + 31) / 32, b64, shA, stream>>>(x, W0, nullptr, nullptr, H, N, 128, 64);
    k_gemm<8><<<(N + 31) / 32, b64, shA, stream>>>(x, sW0, b0, sb0, S, N, 128, 64);
    k_al<<<(N * 16 + 255) / 256, 256, 0, stream>>>(H, as0, ad0, AL, N);
    k_edges<<<gE, 256, 0, stream>>>(AL, csr, dstid, EL, ET);
    k_stats<<<gN4, 256, 0, stream>>>(EL, offs, N);
    k_agg<<<gN4, 256, 0, stream>>>(H, EL, offs, csr, S, N);   // S <- elu(S + gat) = x1

    // ---- layer 1 (input S [N,64])
    k_gemm<8><<<(N + 31) / 32, b64, shB, stream>>>(S, W1, nullptr, nullptr, H, N, 64, 64);
    k_gemm<8><<<(N + 31) / 32, b64, shB, stream>>>(S, sW1, b1, sb1, T, N, 64, 64);
    k_al<<<(N * 16 + 255) / 256, 256, 0, stream>>>(H, as1, ad1, AL, N);
    k_edges<<<gE, 256, 0, stream>>>(AL, csr, dstid, EL, ET);
    k_stats<<<gN4, 256, 0, stream>>>(EL, offs, N);
    k_agg<<<gN4, 256, 0, stream>>>(H, EL, offs, csr, T, N);   // T <- x2

    // ---- layer 2 (input T [N,64])
    k_wt<<<4, 256, 0, stream>>>(W2, as2, ad2, wt);
    k_w2t<<<80, 256, 0, stream>>>(W2, w2t);
    k_gemm<8><<<(N + 127) / 128, b16, shC, stream>>>(T, wt, nullptr, nullptr, AL, N, 64, 16);
    k_gemm<8><<<(N + 47) / 48, b40, shD, stream>>>(T, sW2, b2, sb2, S, N, 64, 40);
    k_edges<<<gE, 256, 0, stream>>>(AL, csr, dstid, EL, ET);
    k_stats<<<gN4, 256, 0, stream>>>(EL, offs, N);
    k_agg2<<<(N + 7) / 8, 512, 0, stream>>>(T, EL, S, w2t, offs, csr, out, N);
}

// Round 3
// 929.945 us; speedup vs baseline: 9.3431x; 1.3596x over previous
//
#include <hip/hip_runtime.h>
#include <hip/hip_bf16.h>
#include <math.h>

#define HEADS 8
#define NEG_SLOPE 0.2f

typedef __attribute__((ext_vector_type(8))) short short8v;
typedef __attribute__((ext_vector_type(4))) float f32x4;

// ---------------------------------------------------------------- CSR build
__global__ void k_initdeg(int* __restrict__ deg, int N) {
    int i = blockIdx.x * 256 + threadIdx.x;
    if (i < N) deg[i] = 1;  // self-loop
}

__global__ void k_count(const int* __restrict__ ei, int* __restrict__ deg, int E) {
    int i = blockIdx.x * 256 + threadIdx.x;
    if (i < E) atomicAdd(&deg[ei[E + i]], 1);  // dst row
}

__global__ void k_scan_block(const int* __restrict__ deg, int* __restrict__ offs,
                             int* __restrict__ bsum, int N) {
    __shared__ int lds[256];
    int tid = threadIdx.x;
    int base = blockIdx.x * 1024 + tid * 4;
    int v0 = (base + 0 < N) ? deg[base + 0] : 0;
    int v1 = (base + 1 < N) ? deg[base + 1] : 0;
    int v2 = (base + 2 < N) ? deg[base + 2] : 0;
    int v3 = (base + 3 < N) ? deg[base + 3] : 0;
    int t01 = v0 + v1;
    int tot = t01 + v2 + v3;
    lds[tid] = tot;
    __syncthreads();
    for (int off = 1; off < 256; off <<= 1) {
        int x = 0;
        if (tid >= off) x = lds[tid - off];
        __syncthreads();
        lds[tid] += x;
        __syncthreads();
    }
    int ex = lds[tid] - tot;
    if (tid == 255) bsum[blockIdx.x] = lds[255];
    if (base + 0 < N) offs[base + 0] = ex;
    if (base + 1 < N) offs[base + 1] = ex + v0;
    if (base + 2 < N) offs[base + 2] = ex + t01;
    if (base + 3 < N) offs[base + 3] = ex + t01 + v2;
}

__global__ void k_scan_top(int* __restrict__ bsum, int nb) {
    if (threadIdx.x == 0 && blockIdx.x == 0) {
        int run = 0;
        for (int b = 0; b < nb; ++b) { int t = bsum[b]; bsum[b] = run; run += t; }
        bsum[nb] = run;
    }
}

__global__ void k_scan_add(int* __restrict__ offs, const int* __restrict__ bsum, int N) {
    int i = blockIdx.x * 256 + threadIdx.x;
    if (i < N) offs[i] += bsum[i >> 10];
    if (i == 0) offs[N] = bsum[(N + 1023) >> 10];
}

__global__ void k_initcur(int* __restrict__ cur, const int* __restrict__ offs, int N) {
    int i = blockIdx.x * 256 + threadIdx.x;
    if (i < N) cur[i] = offs[i];
}

__global__ void k_scatter(const int* __restrict__ ei, int* __restrict__ cur,
                          int* __restrict__ csr, int E, int ET) {
    int i = blockIdx.x * 256 + threadIdx.x;
    if (i >= ET) return;
    int s, d;
    if (i < E) { s = ei[i]; d = ei[E + i]; }
    else       { s = d = i - E; }
    int pos = atomicAdd(&cur[d], 1);
    csr[pos] = s;
}

// ---------------------------------------------------------------- dense GEMM: out[N,M] = X[N,K] @ W[M,K]^T + b1 + b2
template <int RPT>
__global__ void k_gemm(const float* __restrict__ X, const float* __restrict__ W,
                       const float* __restrict__ bias1, const float* __restrict__ bias2,
                       float* __restrict__ out, int N, int K, int M) {
    extern __shared__ float lds[];
    const int Kp = K + 4;
    float* sW = lds;            // M * Kp
    float* sX = lds + M * Kp;   // rows * Kp
    int tx = threadIdx.x, ty = threadIdx.y;
    int nthr = blockDim.x * blockDim.y;
    int tid = ty * blockDim.x + tx;
    int rows = blockDim.y * RPT;
    int r0 = blockIdx.x * rows;

    for (int i = tid * 4; i < M * K; i += nthr * 4) {
        int m = i / K, k = i % K;
        float4 v = *(const float4*)&W[i];
        *(float4*)&sW[m * Kp + k] = v;
    }
    for (int i = tid * 4; i < rows * K; i += nthr * 4) {
        int rl = i / K, k = i % K;
        int gr = r0 + rl;
        float4 v = make_float4(0.f, 0.f, 0.f, 0.f);
        if (gr < N) v = *(const float4*)&X[(size_t)gr * K + k];
        *(float4*)&sX[rl * Kp + k] = v;
    }
    __syncthreads();

    float b = (bias1 ? bias1[tx] : 0.f) + (bias2 ? bias2[tx] : 0.f);
    float acc[RPT];
#pragma unroll
    for (int r = 0; r < RPT; ++r) acc[r] = b;

    for (int k = 0; k < K; k += 4) {
        float4 w4 = *(const float4*)&sW[tx * Kp + k];
#pragma unroll
        for (int r = 0; r < RPT; ++r) {
            float4 x4 = *(const float4*)&sX[(ty * RPT + r) * Kp + k];
            acc[r] += w4.x * x4.x + w4.y * x4.y + w4.z * x4.z + w4.w * x4.w;
        }
    }
#pragma unroll
    for (int r = 0; r < RPT; ++r) {
        int gr = r0 + ty * RPT + r;
        if (gr < N) out[(size_t)gr * M + tx] = acc[r];
    }
}

// ---------------------------------------------------------------- attention logits for layers 0/1 (C=8)
__global__ void k_al(const float* __restrict__ H, const float* __restrict__ as_w,
                     const float* __restrict__ ad_w, float* __restrict__ AL, int N) {
    int t = blockIdx.x * 256 + threadIdx.x;
    int n = t >> 4;
    if (n >= N) return;
    int j = t & 15;
    int hd = j & 7;
    const float* a = (j < 8 ? as_w : ad_w) + hd * 8;
    const float* hp = H + (size_t)n * 64 + hd * 8;
    float sum = 0.f;
#pragma unroll
    for (int c = 0; c < 8; ++c) sum += a[c] * hp[c];
    AL[t] = sum;
}

// wt[j,k] = sum_c a[j][c] * W2[(hd*40+c)*64 + k]   (j<8: a_src, j>=8: a_dst)
__global__ void k_wt(const float* __restrict__ W2, const float* __restrict__ as2,
                     const float* __restrict__ ad2, float* __restrict__ wt) {
    int t = blockIdx.x * 256 + threadIdx.x;
    if (t >= 1024) return;
    int j = t >> 6, k = t & 63;
    int hd = j & 7;
    const float* a = (j < 8 ? as2 : ad2) + hd * 40;
    float sum = 0.f;
    for (int c = 0; c < 40; ++c) sum += a[c] * W2[(size_t)(hd * 40 + c) * 64 + k];
    wt[j * 64 + k] = sum;
}

// w2sw: bf16 W2T pre-swizzled for MFMA B-fragments.
// Logical B[k][col] (k=0..511, col=0..47, cols>=40 zero), B[k][col] = W2[((k>>6)*40+col)*64 + (k&63)].
// Stored at w2sw[((k>>3)*48 + col)*8 + (k&7)].
__global__ void k_w2sw(const float* __restrict__ W2, __hip_bfloat16* __restrict__ w2sw) {
    int t = blockIdx.x * 256 + threadIdx.x;
    if (t >= 64 * 48 * 8) return;
    int j = t & 7;
    int rc = t >> 3;
    int col = rc % 48, c = rc / 48;
    int k = c * 8 + j;
    int hd = k >> 6, kk = k & 63;
    float v = (col < 40) ? W2[(size_t)(hd * 40 + col) * 64 + kk] : 0.f;
    w2sw[t] = __float2bfloat16(v);
}

// ---------------------------------------------------------------- per-node softmax: gather AL directly, write alpha (1 wave/node)
__global__ __launch_bounds__(256) void k_stats2(
    const float* __restrict__ AL, const int* __restrict__ csr,
    const int* __restrict__ offs, float* __restrict__ ALPHA, int N) {
    int wid = threadIdx.x >> 6, lane = threadIdx.x & 63;
    int n = blockIdx.x * 4 + wid;
    if (n >= N) return;
    int off = offs[n], deg = offs[n + 1] - off;
    int el = lane >> 3, hd = lane & 7;  // lane = el*8 + hd
    float ald = AL[(size_t)n * 16 + 8 + hd];

    float m = -1e30f, s = 0.f;
    for (int b0 = 0; b0 < deg; b0 += 8) {
        int e = b0 + el;
        if (e < deg) {
            int src = csr[off + e];
            float v = AL[(size_t)src * 16 + hd] + ald;
            v = v > 0.f ? v : NEG_SLOPE * v;
            float nm = fmaxf(m, v);
            s = s * __expf(m - nm) + __expf(v - nm);
            m = nm;
        }
    }
#pragma unroll
    for (int d = 8; d <= 32; d <<= 1) {
        float mo = __shfl_xor(m, d), so = __shfl_xor(s, d);
        float nm = fmaxf(m, mo);
        s = s * __expf(m - nm) + so * __expf(mo - nm);
        m = nm;
    }
    float sinv = 1.0f / (s + 1e-16f);
    for (int b0 = 0; b0 < deg; b0 += 8) {
        int e = b0 + el;
        if (e < deg) {
            int src = csr[off + e];
            float v = AL[(size_t)src * 16 + hd] + ald;
            v = v > 0.f ? v : NEG_SLOPE * v;
            ALPHA[(size_t)(off + e) * 8 + hd] = __expf(v - m) * sinv;
        }
    }
}

// ---------------------------------------------------------------- layers 0/1 aggregate: acc += alpha * H[src], + skip, ELU (in place on S)
__global__ __launch_bounds__(256) void k_agg(
    const float* __restrict__ H, const float* __restrict__ ALPHA,
    const int* __restrict__ offs, const int* __restrict__ csr,
    float* __restrict__ S, int N) {
    int wid = threadIdx.x >> 6, lane = threadIdx.x & 63;
    int n = blockIdx.x * 4 + wid;
    if (n >= N) return;
    int off = offs[n], deg = offs[n + 1] - off;
    int hd = lane >> 3;
    float acc = 0.f;
    int e = 0;
    for (; e + 4 <= deg; e += 4) {
        int s0 = csr[off + e + 0], s1 = csr[off + e + 1];
        int s2 = csr[off + e + 2], s3 = csr[off + e + 3];
        float a0 = ALPHA[(size_t)(off + e + 0) * 8 + hd];
        float a1 = ALPHA[(size_t)(off + e + 1) * 8 + hd];
        float a2 = ALPHA[(size_t)(off + e + 2) * 8 + hd];
        float a3 = ALPHA[(size_t)(off + e + 3) * 8 + hd];
        float h0 = H[(size_t)s0 * 64 + lane];
        float h1 = H[(size_t)s1 * 64 + lane];
        float h2 = H[(size_t)s2 * 64 + lane];
        float h3 = H[(size_t)s3 * 64 + lane];
        acc += a0 * h0 + a1 * h1 + a2 * h2 + a3 * h3;
    }
    for (; e < deg; ++e) {
        int s0 = csr[off + e];
        float a0 = ALPHA[(size_t)(off + e) * 8 + hd];
        acc += a0 * H[(size_t)s0 * 64 + lane];
    }
    float val = S[(size_t)n * 64 + lane] + acc;
    S[(size_t)n * 64 + lane] = val > 0.f ? val : expm1f(val);
}

// ---------------------------------------------------------------- layer 2: aggregate 512-dim in regs -> bf16 LDS tile -> MFMA projection vs w2sw
// block: 256 threads / 4 waves / 16 nodes
__global__ __launch_bounds__(256) void k_l2m(
    const float* __restrict__ X, const float* __restrict__ ALPHA,
    const float* __restrict__ SK, const __hip_bfloat16* __restrict__ w2sw,
    const int* __restrict__ offs, const int* __restrict__ csr,
    float* __restrict__ out, int N) {
    __shared__ __hip_bfloat16 sA[64 * 16 * 8];  // [chunk][rot-row][8], 16 KB
    __shared__ float sC[16][48];                // 3 KB
    int wid = threadIdx.x >> 6, lane = threadIdx.x & 63;

    // ---- edge aggregation: 4 nodes per wave, 512-dim feature per node
    for (int p = 0; p < 4; ++p) {
        int m = wid * 4 + p;
        int n = blockIdx.x * 16 + m;
        float acc[8] = {0.f, 0.f, 0.f, 0.f, 0.f, 0.f, 0.f, 0.f};
        if (n < N) {
            int off = offs[n], deg = offs[n + 1] - off;
            int e = 0;
            for (; e + 2 <= deg; e += 2) {
                int s0 = csr[off + e], s1 = csr[off + e + 1];
                float xv0 = X[(size_t)s0 * 64 + lane];
                float xv1 = X[(size_t)s1 * 64 + lane];
                const float* a0 = &ALPHA[(size_t)(off + e) * 8];
                const float* a1 = &ALPHA[(size_t)(off + e + 1) * 8];
#pragma unroll
                for (int r = 0; r < 8; ++r) acc[r] += a0[r] * xv0 + a1[r] * xv1;
            }
            if (e < deg) {
                int s0 = csr[off + e];
                float xv0 = X[(size_t)s0 * 64 + lane];
                const float* a0 = &ALPHA[(size_t)(off + e) * 8];
#pragma unroll
                for (int r = 0; r < 8; ++r) acc[r] += a0[r] * xv0;
            }
        }
        // A[m][K], K = r*64 + lane; chunk = K>>3 = r*8 + (lane>>3); rotated row (m+chunk)&15
#pragma unroll
        for (int r = 0; r < 8; ++r) {
            int chunk = r * 8 + (lane >> 3);
            sA[chunk * 128 + ((m + chunk) & 15) * 8 + (lane & 7)] = __float2bfloat16(acc[r]);
        }
    }
    __syncthreads();

    // ---- MFMA projection: waves 0..2 each one 16-col N-tile, K=512
    if (wid < 3) {
        f32x4 cacc = {0.f, 0.f, 0.f, 0.f};
        int grp = lane >> 4;   // 0..3
        int r16 = lane & 15;
#pragma unroll 4
        for (int ks = 0; ks < 16; ++ks) {
            int c = ks * 4 + grp;  // k-chunk: k = c*8 + j
            short8v av = *(const short8v*)&sA[c * 128 + ((r16 + c) & 15) * 8];
            short8v bv = *(const short8v*)&w2sw[(size_t)(c * 48 + wid * 16 + r16) * 8];
            cacc = __builtin_amdgcn_mfma_f32_16x16x32_bf16(av, bv, cacc, 0, 0, 0);
        }
#pragma unroll
        for (int jj = 0; jj < 4; ++jj)
            sC[grp * 4 + jj][wid * 16 + r16] = cacc[jj];
    }
    __syncthreads();

    // ---- epilogue: + skip, log_softmax over 40 outputs
    for (int p = 0; p < 4; ++p) {
        int m = wid * 4 + p;
        int n = blockIdx.x * 16 + m;
        if (n >= N) continue;
        float val = (lane < 40) ? SK[(size_t)n * 40 + lane] + sC[m][lane] * 0.125f : -INFINITY;
        float mx = val;
#pragma unroll
        for (int d = 32; d; d >>= 1) mx = fmaxf(mx, __shfl_xor(mx, d));
        float ex = (lane < 40) ? __expf(val - mx) : 0.f;
        float sm = ex;
#pragma unroll
        for (int d = 32; d; d >>= 1) sm += __shfl_xor(sm, d);
        if (lane < 40) out[(size_t)n * 40 + lane] = val - mx - logf(sm);
    }
}

// ---------------------------------------------------------------- launch
extern "C" void kernel_launch(void* const* d_in, const int* in_sizes, int n_in,
                              void* d_out, int out_size, void* d_ws, size_t ws_size,
                              hipStream_t stream) {
    const float* x   = (const float*)d_in[0];
    const int*   ei  = (const int*)d_in[1];
    const float* W0  = (const float*)d_in[2];
    const float* as0 = (const float*)d_in[3];
    const float* ad0 = (const float*)d_in[4];
    const float* b0  = (const float*)d_in[5];
    const float* sW0 = (const float*)d_in[6];
    const float* sb0 = (const float*)d_in[7];
    const float* W1  = (const float*)d_in[8];
    const float* as1 = (const float*)d_in[9];
    const float* ad1 = (const float*)d_in[10];
    const float* b1  = (const float*)d_in[11];
    const float* sW1 = (const float*)d_in[12];
    const float* sb1 = (const float*)d_in[13];
    const float* W2  = (const float*)d_in[14];
    const float* as2 = (const float*)d_in[15];
    const float* ad2 = (const float*)d_in[16];
    const float* b2  = (const float*)d_in[17];
    const float* sW2 = (const float*)d_in[18];
    const float* sb2 = (const float*)d_in[19];
    float* out = (float*)d_out;

    int N = in_sizes[0] / 128;
    int E = in_sizes[1] / 2;
    int ET = E + N;

    char* wsp = (char*)d_ws;
    size_t woff = 0;
    auto A = [&](size_t nbytes) -> void* {
        void* p = wsp + woff;
        woff = (woff + nbytes + 255) & ~(size_t)255;
        return p;
    };
    int* offs   = (int*)A((size_t)(N + 1) * 4);
    int* cur    = (int*)A((size_t)N * 4);
    int* deg    = (int*)A((size_t)N * 4);
    int* bsum   = (int*)A(4096);
    int* csr    = (int*)A((size_t)ET * 4);
    float* wt   = (float*)A(1024 * 4);
    __hip_bfloat16* w2sw = (__hip_bfloat16*)A(64 * 48 * 8 * 2);
    float* AL   = (float*)A((size_t)N * 16 * 4);
    float* H    = (float*)A((size_t)N * 64 * 4);
    float* S    = (float*)A((size_t)N * 64 * 4);
    float* T    = (float*)A((size_t)N * 64 * 4);
    float* EL   = (float*)A((size_t)ET * 8 * 4);
    (void)ws_size; (void)n_in; (void)out_size;

    // ---- CSR build
    k_initdeg<<<(N + 255) / 256, 256, 0, stream>>>(deg, N);
    k_count<<<(E + 255) / 256, 256, 0, stream>>>(ei, deg, E);
    int nb = (N + 1023) / 1024;
    k_scan_block<<<nb, 256, 0, stream>>>(deg, offs, bsum, N);
    k_scan_top<<<1, 1, 0, stream>>>(bsum, nb);
    k_scan_add<<<(N + 255) / 256, 256, 0, stream>>>(offs, bsum, N);
    k_initcur<<<(N + 255) / 256, 256, 0, stream>>>(cur, offs, N);
    k_scatter<<<(ET + 255) / 256, 256, 0, stream>>>(ei, cur, csr, E, ET);

    dim3 b64(64, 4);
    dim3 b16(16, 16);
    dim3 b40(40, 6);
    size_t shA = (size_t)(64 * 132 + 32 * 132) * 4;  // K=128, M=64
    size_t shB = (size_t)(64 * 68 + 32 * 68) * 4;    // K=64,  M=64
    size_t shC = (size_t)(16 * 68 + 128 * 68) * 4;   // K=64,  M=16
    size_t shD = (size_t)(40 * 68 + 48 * 68) * 4;    // K=64,  M=40

    int gN4 = (N + 3) / 4;

    // ---- layer 0 (input x [N,128])
    k_gemm<8><<<(N + 31) / 32, b64, shA, stream>>>(x, W0, nullptr, nullptr, H, N, 128, 64);
    k_gemm<8><<<(N + 31) / 32, b64, shA, stream>>>(x, sW0, b0, sb0, S, N, 128, 64);
    k_al<<<(N * 16 + 255) / 256, 256, 0, stream>>>(H, as0, ad0, AL, N);
    k_stats2<<<gN4, 256, 0, stream>>>(AL, csr, offs, EL, N);
    k_agg<<<gN4, 256, 0, stream>>>(H, EL, offs, csr, S, N);   // S <- elu(S + gat) = x1

    // ---- layer 1 (input S [N,64])
    k_gemm<8><<<(N + 31) / 32, b64, shB, stream>>>(S, W1, nullptr, nullptr, H, N, 64, 64);
    k_gemm<8><<<(N + 31) / 32, b64, shB, stream>>>(S, sW1, b1, sb1, T, N, 64, 64);
    k_al<<<(N * 16 + 255) / 256, 256, 0, stream>>>(H, as1, ad1, AL, N);
    k_stats2<<<gN4, 256, 0, stream>>>(AL, csr, offs, EL, N);
    k_agg<<<gN4, 256, 0, stream>>>(H, EL, offs, csr, T, N);   // T <- x2

    // ---- layer 2 (input T [N,64])
    k_wt<<<4, 256, 0, stream>>>(W2, as2, ad2, wt);
    k_w2sw<<<96, 256, 0, stream>>>(W2, w2sw);
    k_gemm<8><<<(N + 127) / 128, b16, shC, stream>>>(T, wt, nullptr, nullptr, AL, N, 64, 16);
    k_gemm<8><<<(N + 47) / 48, b40, shD, stream>>>(T, sW2, b2, sb2, S, N, 64, 40);
    k_stats2<<<gN4, 256, 0, stream>>>(AL, csr, offs, EL, N);
    k_l2m<<<(N + 15) / 16, 256, 0, stream>>>(T, EL, S, w2sw, offs, csr, out, N);
}

// Round 4
// 912.361 us; speedup vs baseline: 9.5232x; 1.0193x over previous
//
#include <hip/hip_runtime.h>
#include <hip/hip_bf16.h>
#include <math.h>

#define HEADS 8
#define NEG_SLOPE 0.2f

typedef __attribute__((ext_vector_type(8))) short short8v;
typedef __attribute__((ext_vector_type(4))) float f32x4;

// ---------------------------------------------------------------- CSR build
__global__ void k_initdeg(int* __restrict__ deg, int N) {
    int i = blockIdx.x * 256 + threadIdx.x;
    if (i < N) deg[i] = 1;  // self-loop
}

__global__ void k_count(const int* __restrict__ ei, int* __restrict__ deg, int E) {
    int i = blockIdx.x * 256 + threadIdx.x;
    if (i < E) atomicAdd(&deg[ei[E + i]], 1);  // dst row
}

__global__ void k_scan_block(const int* __restrict__ deg, int* __restrict__ offs,
                             int* __restrict__ bsum, int N) {
    __shared__ int lds[256];
    int tid = threadIdx.x;
    int base = blockIdx.x * 1024 + tid * 4;
    int v0 = (base + 0 < N) ? deg[base + 0] : 0;
    int v1 = (base + 1 < N) ? deg[base + 1] : 0;
    int v2 = (base + 2 < N) ? deg[base + 2] : 0;
    int v3 = (base + 3 < N) ? deg[base + 3] : 0;
    int t01 = v0 + v1;
    int tot = t01 + v2 + v3;
    lds[tid] = tot;
    __syncthreads();
    for (int off = 1; off < 256; off <<= 1) {
        int x = 0;
        if (tid >= off) x = lds[tid - off];
        __syncthreads();
        lds[tid] += x;
        __syncthreads();
    }
    int ex = lds[tid] - tot;
    if (tid == 255) bsum[blockIdx.x] = lds[255];
    if (base + 0 < N) offs[base + 0] = ex;
    if (base + 1 < N) offs[base + 1] = ex + v0;
    if (base + 2 < N) offs[base + 2] = ex + t01;
    if (base + 3 < N) offs[base + 3] = ex + t01 + v2;
}

__global__ void k_scan_top(int* __restrict__ bsum, int nb) {
    if (threadIdx.x == 0 && blockIdx.x == 0) {
        int run = 0;
        for (int b = 0; b < nb; ++b) { int t = bsum[b]; bsum[b] = run; run += t; }
        bsum[nb] = run;
    }
}

__global__ void k_scan_add(int* __restrict__ offs, const int* __restrict__ bsum, int N) {
    int i = blockIdx.x * 256 + threadIdx.x;
    if (i < N) offs[i] += bsum[i >> 10];
    if (i == 0) offs[N] = bsum[(N + 1023) >> 10];
}

__global__ void k_initcur(int* __restrict__ cur, const int* __restrict__ offs, int N) {
    int i = blockIdx.x * 256 + threadIdx.x;
    if (i < N) cur[i] = offs[i];
}

__global__ void k_scatter(const int* __restrict__ ei, int* __restrict__ cur,
                          int* __restrict__ csr, int E, int ET) {
    int i = blockIdx.x * 256 + threadIdx.x;
    if (i >= ET) return;
    int s, d;
    if (i < E) { s = ei[i]; d = ei[E + i]; }
    else       { s = d = i - E; }
    int pos = atomicAdd(&cur[d], 1);
    csr[pos] = s;
}

// ---------------------------------------------------------------- dense GEMM: out[N,M] = X[N,K] @ W[M,K]^T + b1 + b2
template <int RPT>
__global__ void k_gemm(const float* __restrict__ X, const float* __restrict__ W,
                       const float* __restrict__ bias1, const float* __restrict__ bias2,
                       float* __restrict__ out, int N, int K, int M) {
    extern __shared__ float lds[];
    const int Kp = K + 4;
    float* sW = lds;            // M * Kp
    float* sX = lds + M * Kp;   // rows * Kp
    int tx = threadIdx.x, ty = threadIdx.y;
    int nthr = blockDim.x * blockDim.y;
    int tid = ty * blockDim.x + tx;
    int rows = blockDim.y * RPT;
    int r0 = blockIdx.x * rows;

    for (int i = tid * 4; i < M * K; i += nthr * 4) {
        int m = i / K, k = i % K;
        float4 v = *(const float4*)&W[i];
        *(float4*)&sW[m * Kp + k] = v;
    }
    for (int i = tid * 4; i < rows * K; i += nthr * 4) {
        int rl = i / K, k = i % K;
        int gr = r0 + rl;
        float4 v = make_float4(0.f, 0.f, 0.f, 0.f);
        if (gr < N) v = *(const float4*)&X[(size_t)gr * K + k];
        *(float4*)&sX[rl * Kp + k] = v;
    }
    __syncthreads();

    float b = (bias1 ? bias1[tx] : 0.f) + (bias2 ? bias2[tx] : 0.f);
    float acc[RPT];
#pragma unroll
    for (int r = 0; r < RPT; ++r) acc[r] = b;

    for (int k = 0; k < K; k += 4) {
        float4 w4 = *(const float4*)&sW[tx * Kp + k];
#pragma unroll
        for (int r = 0; r < RPT; ++r) {
            float4 x4 = *(const float4*)&sX[(ty * RPT + r) * Kp + k];
            acc[r] += w4.x * x4.x + w4.y * x4.y + w4.z * x4.z + w4.w * x4.w;
        }
    }
#pragma unroll
    for (int r = 0; r < RPT; ++r) {
        int gr = r0 + ty * RPT + r;
        if (gr < N) out[(size_t)gr * M + tx] = acc[r];
    }
}

// ---------------------------------------------------------------- attention logits for layers 0/1 (C=8)
__global__ void k_al(const float* __restrict__ H, const float* __restrict__ as_w,
                     const float* __restrict__ ad_w, float* __restrict__ AL, int N) {
    int t = blockIdx.x * 256 + threadIdx.x;
    int n = t >> 4;
    if (n >= N) return;
    int j = t & 15;
    int hd = j & 7;
    const float* a = (j < 8 ? as_w : ad_w) + hd * 8;
    const float* hp = H + (size_t)n * 64 + hd * 8;
    float sum = 0.f;
#pragma unroll
    for (int c = 0; c < 8; ++c) sum += a[c] * hp[c];
    AL[t] = sum;
}

// wt[j,k] = sum_c a[j][c] * W2[(hd*40+c)*64 + k]   (j<8: a_src, j>=8: a_dst)
__global__ void k_wt(const float* __restrict__ W2, const float* __restrict__ as2,
                     const float* __restrict__ ad2, float* __restrict__ wt) {
    int t = blockIdx.x * 256 + threadIdx.x;
    if (t >= 1024) return;
    int j = t >> 6, k = t & 63;
    int hd = j & 7;
    const float* a = (j < 8 ? as2 : ad2) + hd * 40;
    float sum = 0.f;
    for (int c = 0; c < 40; ++c) sum += a[c] * W2[(size_t)(hd * 40 + c) * 64 + k];
    wt[j * 64 + k] = sum;
}

// w2sw: bf16 W2T pre-swizzled for MFMA B-fragments.
// Logical B[k][col] (k=0..511, col=0..47, cols>=40 zero), B[k][col] = W2[((k>>6)*40+col)*64 + (k&63)].
// Stored at w2sw[((k>>3)*48 + col)*8 + (k&7)].
__global__ void k_w2sw(const float* __restrict__ W2, __hip_bfloat16* __restrict__ w2sw) {
    int t = blockIdx.x * 256 + threadIdx.x;
    if (t >= 64 * 48 * 8) return;
    int j = t & 7;
    int rc = t >> 3;
    int col = rc % 48, c = rc / 48;
    int k = c * 8 + j;
    int hd = k >> 6, kk = k & 63;
    float v = (col < 40) ? W2[(size_t)(hd * 40 + col) * 64 + kk] : 0.f;
    w2sw[t] = __float2bfloat16(v);
}

// ---------------------------------------------------------------- layers 0/1: fused softmax + aggregate + skip + ELU (in place on S)
// 1 wave/node. Pass 1: gather (src, leaky-logit) for edges into registers
// (stats layout: lane = el*8 + hd), online max/sum, shfl_xor merge.
// Pass 2: alpha from cached registers, shfl-redistribute to feature layout,
// coalesced H-row gather + FMA. deg>64 falls back to re-gather (rare).
__global__ __launch_bounds__(256) void k_fused(
    const float* __restrict__ H, const float* __restrict__ AL,
    const int* __restrict__ offs, const int* __restrict__ csr,
    float* __restrict__ S, int N) {
    int wid = threadIdx.x >> 6, lane = threadIdx.x & 63;
    int n = blockIdx.x * 4 + wid;
    if (n >= N) return;
    int off = offs[n], deg = offs[n + 1] - off;
    int el = lane >> 3, hd = lane & 7;
    float ald = AL[(size_t)n * 16 + 8 + hd];

    float vv[8]; int ss[8];
    float m = -1e30f, s = 0.f;
#pragma unroll
    for (int i = 0; i < 8; ++i) {
        int e = i * 8 + el;
        float v = -1e30f; int src = 0;
        if (e < deg) {
            src = csr[off + e];
            float t = AL[(size_t)src * 16 + hd] + ald;
            v = t > 0.f ? t : NEG_SLOPE * t;
            float nm = fmaxf(m, v);
            s = s * __expf(m - nm) + __expf(v - nm);
            m = nm;
        }
        ss[i] = src; vv[i] = v;
    }
    for (int b0 = 64; b0 < deg; b0 += 8) {
        int e = b0 + el;
        if (e < deg) {
            int src = csr[off + e];
            float t = AL[(size_t)src * 16 + hd] + ald;
            t = t > 0.f ? t : NEG_SLOPE * t;
            float nm = fmaxf(m, t);
            s = s * __expf(m - nm) + __expf(t - nm);
            m = nm;
        }
    }
#pragma unroll
    for (int d = 8; d <= 32; d <<= 1) {
        float mo = __shfl_xor(m, d), so = __shfl_xor(s, d);
        float nm = fmaxf(m, mo);
        s = s * __expf(m - nm) + so * __expf(mo - nm);
        m = nm;
    }
    float sinv = 1.0f / (s + 1e-16f);

    float acc = 0.f;
    int fhd = lane >> 3;  // feature-layout head
#pragma unroll
    for (int i = 0; i < 8; ++i) {
        int b0 = i * 8;
        if (b0 >= deg) break;
        float alpha = (b0 + el < deg) ? __expf(vv[i] - m) * sinv : 0.f;
        int cnt = min(deg - b0, 8);
        for (int j = 0; j < cnt; ++j) {
            int s0 = __shfl(ss[i], j * 8);
            float a0 = __shfl(alpha, j * 8 + fhd);
            acc += a0 * H[(size_t)s0 * 64 + lane];
        }
    }
    for (int b0 = 64; b0 < deg; b0 += 8) {
        int e = b0 + el;
        float alpha = 0.f; int src = 0;
        if (e < deg) {
            src = csr[off + e];
            float t = AL[(size_t)src * 16 + hd] + ald;
            t = t > 0.f ? t : NEG_SLOPE * t;
            alpha = __expf(t - m) * sinv;
        }
        int cnt = min(deg - b0, 8);
        for (int j = 0; j < cnt; ++j) {
            int s0 = __shfl(src, j * 8);
            float a0 = __shfl(alpha, j * 8 + fhd);
            acc += a0 * H[(size_t)s0 * 64 + lane];
        }
    }
    float val = S[(size_t)n * 64 + lane] + acc;
    S[(size_t)n * 64 + lane] = val > 0.f ? val : expm1f(val);
}

// ---------------------------------------------------------------- layer 2: fused softmax + 512-dim aggregate -> bf16 LDS tile -> MFMA vs w2sw
// block: 256 threads / 4 waves / 16 nodes
__global__ __launch_bounds__(256) void k_l2f(
    const float* __restrict__ X, const float* __restrict__ AL,
    const float* __restrict__ SK, const __hip_bfloat16* __restrict__ w2sw,
    const int* __restrict__ offs, const int* __restrict__ csr,
    float* __restrict__ out, int N) {
    __shared__ __hip_bfloat16 sA[64 * 16 * 8];  // [chunk][rot-row][8], 16 KB
    __shared__ float sC[16][48];                // 3 KB
    int wid = threadIdx.x >> 6, lane = threadIdx.x & 63;
    int el = lane >> 3, hd = lane & 7;

    // ---- edge aggregation: 4 nodes per wave, 512-dim feature per node
    for (int p = 0; p < 4; ++p) {
        int mrow = wid * 4 + p;
        int n = blockIdx.x * 16 + mrow;
        float acc[8] = {0.f, 0.f, 0.f, 0.f, 0.f, 0.f, 0.f, 0.f};
        if (n < N) {
            int off = offs[n], deg = offs[n + 1] - off;
            float ald = AL[(size_t)n * 16 + 8 + hd];

            float vv[8]; int ss[8];
            float m = -1e30f, s = 0.f;
#pragma unroll
            for (int i = 0; i < 8; ++i) {
                int e = i * 8 + el;
                float v = -1e30f; int src = 0;
                if (e < deg) {
                    src = csr[off + e];
                    float t = AL[(size_t)src * 16 + hd] + ald;
                    v = t > 0.f ? t : NEG_SLOPE * t;
                    float nm = fmaxf(m, v);
                    s = s * __expf(m - nm) + __expf(v - nm);
                    m = nm;
                }
                ss[i] = src; vv[i] = v;
            }
            for (int b0 = 64; b0 < deg; b0 += 8) {
                int e = b0 + el;
                if (e < deg) {
                    int src = csr[off + e];
                    float t = AL[(size_t)src * 16 + hd] + ald;
                    t = t > 0.f ? t : NEG_SLOPE * t;
                    float nm = fmaxf(m, t);
                    s = s * __expf(m - nm) + __expf(t - nm);
                    m = nm;
                }
            }
#pragma unroll
            for (int d = 8; d <= 32; d <<= 1) {
                float mo = __shfl_xor(m, d), so = __shfl_xor(s, d);
                float nm = fmaxf(m, mo);
                s = s * __expf(m - nm) + so * __expf(mo - nm);
                m = nm;
            }
            float sinv = 1.0f / (s + 1e-16f);

#pragma unroll
            for (int i = 0; i < 8; ++i) {
                int b0 = i * 8;
                if (b0 >= deg) break;
                float alpha = (b0 + el < deg) ? __expf(vv[i] - m) * sinv : 0.f;
                int cnt = min(deg - b0, 8);
                for (int j = 0; j < cnt; ++j) {
                    int s0 = __shfl(ss[i], j * 8);
                    float xv = X[(size_t)s0 * 64 + lane];
#pragma unroll
                    for (int r = 0; r < 8; ++r)
                        acc[r] += __shfl(alpha, j * 8 + r) * xv;
                }
            }
            for (int b0 = 64; b0 < deg; b0 += 8) {
                int e = b0 + el;
                float alpha = 0.f; int src = 0;
                if (e < deg) {
                    src = csr[off + e];
                    float t = AL[(size_t)src * 16 + hd] + ald;
                    t = t > 0.f ? t : NEG_SLOPE * t;
                    alpha = __expf(t - m) * sinv;
                }
                int cnt = min(deg - b0, 8);
                for (int j = 0; j < cnt; ++j) {
                    int s0 = __shfl(src, j * 8);
                    float xv = X[(size_t)s0 * 64 + lane];
#pragma unroll
                    for (int r = 0; r < 8; ++r)
                        acc[r] += __shfl(alpha, j * 8 + r) * xv;
                }
            }
        }
        // A[m][K], K = r*64 + lane; chunk = K>>3 = r*8 + (lane>>3); rotated row (m+chunk)&15
#pragma unroll
        for (int r = 0; r < 8; ++r) {
            int chunk = r * 8 + (lane >> 3);
            sA[chunk * 128 + ((mrow + chunk) & 15) * 8 + (lane & 7)] = __float2bfloat16(acc[r]);
        }
    }
    __syncthreads();

    // ---- MFMA projection: waves 0..2 each one 16-col N-tile, K=512
    if (wid < 3) {
        f32x4 cacc = {0.f, 0.f, 0.f, 0.f};
        int grp = lane >> 4;   // 0..3
        int r16 = lane & 15;
#pragma unroll 4
        for (int ks = 0; ks < 16; ++ks) {
            int c = ks * 4 + grp;  // k-chunk: k = c*8 + j
            short8v av = *(const short8v*)&sA[c * 128 + ((r16 + c) & 15) * 8];
            short8v bv = *(const short8v*)&w2sw[(size_t)(c * 48 + wid * 16 + r16) * 8];
            cacc = __builtin_amdgcn_mfma_f32_16x16x32_bf16(av, bv, cacc, 0, 0, 0);
        }
#pragma unroll
        for (int jj = 0; jj < 4; ++jj)
            sC[grp * 4 + jj][wid * 16 + r16] = cacc[jj];
    }
    __syncthreads();

    // ---- epilogue: + skip, log_softmax over 40 outputs
    for (int p = 0; p < 4; ++p) {
        int mrow = wid * 4 + p;
        int n = blockIdx.x * 16 + mrow;
        if (n >= N) continue;
        float val = (lane < 40) ? SK[(size_t)n * 40 + lane] + sC[mrow][lane] * 0.125f : -INFINITY;
        float mx = val;
#pragma unroll
        for (int d = 32; d; d >>= 1) mx = fmaxf(mx, __shfl_xor(mx, d));
        float ex = (lane < 40) ? __expf(val - mx) : 0.f;
        float sm = ex;
#pragma unroll
        for (int d = 32; d; d >>= 1) sm += __shfl_xor(sm, d);
        if (lane < 40) out[(size_t)n * 40 + lane] = val - mx - logf(sm);
    }
}

// ---------------------------------------------------------------- launch
extern "C" void kernel_launch(void* const* d_in, const int* in_sizes, int n_in,
                              void* d_out, int out_size, void* d_ws, size_t ws_size,
                              hipStream_t stream) {
    const float* x   = (const float*)d_in[0];
    const int*   ei  = (const int*)d_in[1];
    const float* W0  = (const float*)d_in[2];
    const float* as0 = (const float*)d_in[3];
    const float* ad0 = (const float*)d_in[4];
    const float* b0  = (const float*)d_in[5];
    const float* sW0 = (const float*)d_in[6];
    const float* sb0 = (const float*)d_in[7];
    const float* W1  = (const float*)d_in[8];
    const float* as1 = (const float*)d_in[9];
    const float* ad1 = (const float*)d_in[10];
    const float* b1  = (const float*)d_in[11];
    const float* sW1 = (const float*)d_in[12];
    const float* sb1 = (const float*)d_in[13];
    const float* W2  = (const float*)d_in[14];
    const float* as2 = (const float*)d_in[15];
    const float* ad2 = (const float*)d_in[16];
    const float* b2  = (const float*)d_in[17];
    const float* sW2 = (const float*)d_in[18];
    const float* sb2 = (const float*)d_in[19];
    float* out = (float*)d_out;

    int N = in_sizes[0] / 128;
    int E = in_sizes[1] / 2;
    int ET = E + N;

    char* wsp = (char*)d_ws;
    size_t woff = 0;
    auto A = [&](size_t nbytes) -> void* {
        void* p = wsp + woff;
        woff = (woff + nbytes + 255) & ~(size_t)255;
        return p;
    };
    int* offs   = (int*)A((size_t)(N + 1) * 4);
    int* cur    = (int*)A((size_t)N * 4);
    int* deg    = (int*)A((size_t)N * 4);
    int* bsum   = (int*)A(4096);
    int* csr    = (int*)A((size_t)ET * 4);
    float* wt   = (float*)A(1024 * 4);
    __hip_bfloat16* w2sw = (__hip_bfloat16*)A(64 * 48 * 8 * 2);
    float* AL   = (float*)A((size_t)N * 16 * 4);
    float* H    = (float*)A((size_t)N * 64 * 4);
    float* S    = (float*)A((size_t)N * 64 * 4);
    float* T    = (float*)A((size_t)N * 64 * 4);
    (void)ws_size; (void)n_in; (void)out_size;

    // ---- CSR build
    k_initdeg<<<(N + 255) / 256, 256, 0, stream>>>(deg, N);
    k_count<<<(E + 255) / 256, 256, 0, stream>>>(ei, deg, E);
    int nb = (N + 1023) / 1024;
    k_scan_block<<<nb, 256, 0, stream>>>(deg, offs, bsum, N);
    k_scan_top<<<1, 1, 0, stream>>>(bsum, nb);
    k_scan_add<<<(N + 255) / 256, 256, 0, stream>>>(offs, bsum, N);
    k_initcur<<<(N + 255) / 256, 256, 0, stream>>>(cur, offs, N);
    k_scatter<<<(ET + 255) / 256, 256, 0, stream>>>(ei, cur, csr, E, ET);

    dim3 b64(64, 4);
    dim3 b16(16, 16);
    dim3 b40(40, 6);
    size_t shA = (size_t)(64 * 132 + 32 * 132) * 4;  // K=128, M=64
    size_t shB = (size_t)(64 * 68 + 32 * 68) * 4;    // K=64,  M=64
    size_t shC = (size_t)(16 * 68 + 128 * 68) * 4;   // K=64,  M=16
    size_t shD = (size_t)(40 * 68 + 48 * 68) * 4;    // K=64,  M=40

    int gN4 = (N + 3) / 4;

    // ---- layer 0 (input x [N,128])
    k_gemm<8><<<(N + 31) / 32, b64, shA, stream>>>(x, W0, nullptr, nullptr, H, N, 128, 64);
    k_gemm<8><<<(N + 31) / 32, b64, shA, stream>>>(x, sW0, b0, sb0, S, N, 128, 64);
    k_al<<<(N * 16 + 255) / 256, 256, 0, stream>>>(H, as0, ad0, AL, N);
    k_fused<<<gN4, 256, 0, stream>>>(H, AL, offs, csr, S, N);   // S <- elu(S + gat) = x1

    // ---- layer 1 (input S [N,64])
    k_gemm<8><<<(N + 31) / 32, b64, shB, stream>>>(S, W1, nullptr, nullptr, H, N, 64, 64);
    k_gemm<8><<<(N + 31) / 32, b64, shB, stream>>>(S, sW1, b1, sb1, T, N, 64, 64);
    k_al<<<(N * 16 + 255) / 256, 256, 0, stream>>>(H, as1, ad1, AL, N);
    k_fused<<<gN4, 256, 0, stream>>>(H, AL, offs, csr, T, N);   // T <- x2

    // ---- layer 2 (input T [N,64])
    k_wt<<<4, 256, 0, stream>>>(W2, as2, ad2, wt);
    k_w2sw<<<96, 256, 0, stream>>>(W2, w2sw);
    k_gemm<8><<<(N + 127) / 128, b16, shC, stream>>>(T, wt, nullptr, nullptr, AL, N, 64, 16);
    k_gemm<8><<<(N + 47) / 48, b40, shD, stream>>>(T, sW2, b2, sb2, S, N, 64, 40);
    k_l2f<<<(N + 15) / 16, 256, 0, stream>>>(T, AL, S, w2sw, offs, csr, out, N);
}

// Round 5
// 809.042 us; speedup vs baseline: 10.7394x; 1.1277x over previous
//
#include <hip/hip_runtime.h>
#include <hip/hip_bf16.h>
#include <math.h>

#define HEADS 8
#define NEG_SLOPE 0.2f

typedef __attribute__((ext_vector_type(8))) short short8v;
typedef __attribute__((ext_vector_type(4))) float f32x4;

// ---------------------------------------------------------------- CSR build
__global__ void k_initdeg(int* __restrict__ deg, int N) {
    int i = blockIdx.x * 256 + threadIdx.x;
    if (i < N) deg[i] = 1;  // self-loop
}

__global__ void k_count(const int* __restrict__ ei, int* __restrict__ deg, int E) {
    int i = blockIdx.x * 256 + threadIdx.x;
    if (i < E) atomicAdd(&deg[ei[E + i]], 1);  // dst row
}

__global__ void k_scan_block(const int* __restrict__ deg, int* __restrict__ offs,
                             int* __restrict__ bsum, int N) {
    __shared__ int lds[256];
    int tid = threadIdx.x;
    int base = blockIdx.x * 1024 + tid * 4;
    int v0 = (base + 0 < N) ? deg[base + 0] : 0;
    int v1 = (base + 1 < N) ? deg[base + 1] : 0;
    int v2 = (base + 2 < N) ? deg[base + 2] : 0;
    int v3 = (base + 3 < N) ? deg[base + 3] : 0;
    int t01 = v0 + v1;
    int tot = t01 + v2 + v3;
    lds[tid] = tot;
    __syncthreads();
    for (int off = 1; off < 256; off <<= 1) {
        int x = 0;
        if (tid >= off) x = lds[tid - off];
        __syncthreads();
        lds[tid] += x;
        __syncthreads();
    }
    int ex = lds[tid] - tot;
    if (tid == 255) bsum[blockIdx.x] = lds[255];
    if (base + 0 < N) offs[base + 0] = ex;
    if (base + 1 < N) offs[base + 1] = ex + v0;
    if (base + 2 < N) offs[base + 2] = ex + t01;
    if (base + 3 < N) offs[base + 3] = ex + t01 + v2;
}

__global__ void k_scan_top(int* __restrict__ bsum, int nb) {
    if (threadIdx.x == 0 && blockIdx.x == 0) {
        int run = 0;
        for (int b = 0; b < nb; ++b) { int t = bsum[b]; bsum[b] = run; run += t; }
        bsum[nb] = run;
    }
}

__global__ void k_scan_add(int* __restrict__ offs, const int* __restrict__ bsum, int N) {
    int i = blockIdx.x * 256 + threadIdx.x;
    if (i < N) offs[i] += bsum[i >> 10];
    if (i == 0) offs[N] = bsum[(N + 1023) >> 10];
}

__global__ void k_initcur(int* __restrict__ cur, const int* __restrict__ offs, int N) {
    int i = blockIdx.x * 256 + threadIdx.x;
    if (i < N) cur[i] = offs[i];
}

__global__ void k_scatter(const int* __restrict__ ei, int* __restrict__ cur,
                          int* __restrict__ csr, int E, int ET) {
    int i = blockIdx.x * 256 + threadIdx.x;
    if (i >= ET) return;
    int s, d;
    if (i < E) { s = ei[i]; d = ei[E + i]; }
    else       { s = d = i - E; }
    int pos = atomicAdd(&cur[d], 1);
    csr[pos] = s;
}

// ---------------------------------------------------------------- register-blocked GEMM
// out[N,M] = X[N,K]@W[M,K]^T + b1 + b2.  block dim3(16,16); 64 rows/block.
// Thread (tx,ty): rows ty*4..+3, cols tx+16*jc (jc<CPT). K-tiled by 64.
template <int CPT>
__global__ __launch_bounds__(256) void k_gemm2(
    const float* __restrict__ X, const float* __restrict__ W,
    const float* __restrict__ bias1, const float* __restrict__ bias2,
    float* __restrict__ out, int N, int K, int M) {
    __shared__ float sW[CPT * 16][68];
    __shared__ float sX[64][68];
    int tx = threadIdx.x, ty = threadIdx.y;
    int tid = ty * 16 + tx;
    int r0 = blockIdx.x * 64;

    float acc[4][CPT];
#pragma unroll
    for (int jc = 0; jc < CPT; ++jc) {
        int col = tx + 16 * jc;
        float b = 0.f;
        if (col < M) {
            if (bias1) b += bias1[col];
            if (bias2) b += bias2[col];
        }
#pragma unroll
        for (int jr = 0; jr < 4; ++jr) acc[jr][jc] = b;
    }

    for (int k0 = 0; k0 < K; k0 += 64) {
        __syncthreads();
        for (int idx = tid; idx < CPT * 16 * 16; idx += 256) {
            int c = idx >> 4, kq = (idx & 15) * 4;
            float4 v = make_float4(0.f, 0.f, 0.f, 0.f);
            if (c < M) v = *(const float4*)&W[(size_t)c * K + k0 + kq];
            *(float4*)&sW[c][kq] = v;
        }
        for (int idx = tid; idx < 64 * 16; idx += 256) {
            int r = idx >> 4, kq = (idx & 15) * 4;
            int gr = r0 + r;
            float4 v = make_float4(0.f, 0.f, 0.f, 0.f);
            if (gr < N) v = *(const float4*)&X[(size_t)gr * K + k0 + kq];
            *(float4*)&sX[r][kq] = v;
        }
        __syncthreads();

        for (int k = 0; k < 64; k += 4) {
            float4 xr[4], wc[CPT];
#pragma unroll
            for (int jr = 0; jr < 4; ++jr) xr[jr] = *(const float4*)&sX[ty * 4 + jr][k];
#pragma unroll
            for (int jc = 0; jc < CPT; ++jc) wc[jc] = *(const float4*)&sW[tx + 16 * jc][k];
#pragma unroll
            for (int jc = 0; jc < CPT; ++jc)
#pragma unroll
                for (int jr = 0; jr < 4; ++jr)
                    acc[jr][jc] += wc[jc].x * xr[jr].x + wc[jc].y * xr[jr].y +
                                   wc[jc].z * xr[jr].z + wc[jc].w * xr[jr].w;
        }
    }

#pragma unroll
    for (int jr = 0; jr < 4; ++jr) {
        int gr = r0 + ty * 4 + jr;
        if (gr >= N) continue;
#pragma unroll
        for (int jc = 0; jc < CPT; ++jc) {
            int col = tx + 16 * jc;
            if (col < M) out[(size_t)gr * M + col] = acc[jr][jc];
        }
    }
}

// ---------------------------------------------------------------- attention logits for layers 0/1 (C=8)
__global__ void k_al(const float* __restrict__ H, const float* __restrict__ as_w,
                     const float* __restrict__ ad_w, float* __restrict__ AL, int N) {
    int t = blockIdx.x * 256 + threadIdx.x;
    int n = t >> 4;
    if (n >= N) return;
    int j = t & 15;
    int hd = j & 7;
    const float* a = (j < 8 ? as_w : ad_w) + hd * 8;
    const float* hp = H + (size_t)n * 64 + hd * 8;
    float sum = 0.f;
#pragma unroll
    for (int c = 0; c < 8; ++c) sum += a[c] * hp[c];
    AL[t] = sum;
}

// wt[j,k] = sum_c a[j][c] * W2[(hd*40+c)*64 + k]   (j<8: a_src, j>=8: a_dst)
__global__ void k_wt(const float* __restrict__ W2, const float* __restrict__ as2,
                     const float* __restrict__ ad2, float* __restrict__ wt) {
    int t = blockIdx.x * 256 + threadIdx.x;
    if (t >= 1024) return;
    int j = t >> 6, k = t & 63;
    int hd = j & 7;
    const float* a = (j < 8 ? as2 : ad2) + hd * 40;
    float sum = 0.f;
    for (int c = 0; c < 40; ++c) sum += a[c] * W2[(size_t)(hd * 40 + c) * 64 + k];
    wt[j * 64 + k] = sum;
}

// w2sw: bf16 W2T pre-swizzled for MFMA B-fragments.
__global__ void k_w2sw(const float* __restrict__ W2, __hip_bfloat16* __restrict__ w2sw) {
    int t = blockIdx.x * 256 + threadIdx.x;
    if (t >= 64 * 48 * 8) return;
    int j = t & 7;
    int rc = t >> 3;
    int col = rc % 48, c = rc / 48;
    int k = c * 8 + j;
    int hd = k >> 6, kk = k & 63;
    float v = (col < 40) ? W2[(size_t)(hd * 40 + col) * 64 + kk] : 0.f;
    w2sw[t] = __float2bfloat16(v);
}

// ---------------------------------------------------------------- layers 0/1: fused softmax + aggregate + skip + ELU
__global__ __launch_bounds__(256) void k_fused(
    const float* __restrict__ H, const float* __restrict__ AL,
    const int* __restrict__ offs, const int* __restrict__ csr,
    float* __restrict__ S, int N) {
    int wid = threadIdx.x >> 6, lane = threadIdx.x & 63;
    int n = blockIdx.x * 4 + wid;
    if (n >= N) return;
    int off = offs[n], deg = offs[n + 1] - off;
    int el = lane >> 3, hd = lane & 7;
    float ald = AL[(size_t)n * 16 + 8 + hd];

    float vv[8]; int ss[8];
    float m = -1e30f, s = 0.f;
#pragma unroll
    for (int i = 0; i < 8; ++i) {
        int e = i * 8 + el;
        float v = -1e30f; int src = 0;
        if (e < deg) {
            src = csr[off + e];
            float t = AL[(size_t)src * 16 + hd] + ald;
            v = t > 0.f ? t : NEG_SLOPE * t;
            float nm = fmaxf(m, v);
            s = s * __expf(m - nm) + __expf(v - nm);
            m = nm;
        }
        ss[i] = src; vv[i] = v;
    }
    for (int b0 = 64; b0 < deg; b0 += 8) {
        int e = b0 + el;
        if (e < deg) {
            int src = csr[off + e];
            float t = AL[(size_t)src * 16 + hd] + ald;
            t = t > 0.f ? t : NEG_SLOPE * t;
            float nm = fmaxf(m, t);
            s = s * __expf(m - nm) + __expf(t - nm);
            m = nm;
        }
    }
#pragma unroll
    for (int d = 8; d <= 32; d <<= 1) {
        float mo = __shfl_xor(m, d), so = __shfl_xor(s, d);
        float nm = fmaxf(m, mo);
        s = s * __expf(m - nm) + so * __expf(mo - nm);
        m = nm;
    }
    float sinv = 1.0f / (s + 1e-16f);

    float acc = 0.f;
    int fhd = lane >> 3;  // feature-layout head
#pragma unroll
    for (int i = 0; i < 8; ++i) {
        int b0 = i * 8;
        if (b0 >= deg) break;
        float alpha = (b0 + el < deg) ? __expf(vv[i] - m) * sinv : 0.f;
#pragma unroll
        for (int j = 0; j < 8; ++j) {  // fixed bound: invalid slots have alpha 0, src 0
            int s0 = __shfl(ss[i], j * 8);
            float a0 = __shfl(alpha, j * 8 + fhd);
            acc += a0 * H[(size_t)s0 * 64 + lane];
        }
    }
    for (int b0 = 64; b0 < deg; b0 += 8) {
        int e = b0 + el;
        float alpha = 0.f; int src = 0;
        if (e < deg) {
            src = csr[off + e];
            float t = AL[(size_t)src * 16 + hd] + ald;
            t = t > 0.f ? t : NEG_SLOPE * t;
            alpha = __expf(t - m) * sinv;
        }
#pragma unroll
        for (int j = 0; j < 8; ++j) {
            int s0 = __shfl(src, j * 8);
            float a0 = __shfl(alpha, j * 8 + fhd);
            acc += a0 * H[(size_t)s0 * 64 + lane];
        }
    }
    float val = S[(size_t)n * 64 + lane] + acc;
    S[(size_t)n * 64 + lane] = val > 0.f ? val : expm1f(val);
}

// ---------------------------------------------------------------- layer 2: fused softmax + 512-dim aggregate -> bf16 LDS -> MFMA vs w2sw
__global__ __launch_bounds__(256) void k_l2f(
    const float* __restrict__ X, const float* __restrict__ AL,
    const float* __restrict__ SK, const __hip_bfloat16* __restrict__ w2sw,
    const int* __restrict__ offs, const int* __restrict__ csr,
    float* __restrict__ out, int N) {
    __shared__ __hip_bfloat16 sA[64 * 16 * 8];  // [chunk][rot-row][8], 16 KB
    __shared__ float sC[16][48];                // 3 KB
    __shared__ float sAl[4][64];                // per-wave alpha group, 1 KB
    int wid = threadIdx.x >> 6, lane = threadIdx.x & 63;
    int el = lane >> 3, hd = lane & 7;

    for (int p = 0; p < 4; ++p) {
        int mrow = wid * 4 + p;
        int n = blockIdx.x * 16 + mrow;
        float acc[8] = {0.f, 0.f, 0.f, 0.f, 0.f, 0.f, 0.f, 0.f};
        if (n < N) {
            int off = offs[n], deg = offs[n + 1] - off;
            float ald = AL[(size_t)n * 16 + 8 + hd];

            float vv[8]; int ss[8];
            float m = -1e30f, s = 0.f;
#pragma unroll
            for (int i = 0; i < 8; ++i) {
                int e = i * 8 + el;
                float v = -1e30f; int src = 0;
                if (e < deg) {
                    src = csr[off + e];
                    float t = AL[(size_t)src * 16 + hd] + ald;
                    v = t > 0.f ? t : NEG_SLOPE * t;
                    float nm = fmaxf(m, v);
                    s = s * __expf(m - nm) + __expf(v - nm);
                    m = nm;
                }
                ss[i] = src; vv[i] = v;
            }
            for (int b0 = 64; b0 < deg; b0 += 8) {
                int e = b0 + el;
                if (e < deg) {
                    int src = csr[off + e];
                    float t = AL[(size_t)src * 16 + hd] + ald;
                    t = t > 0.f ? t : NEG_SLOPE * t;
                    float nm = fmaxf(m, t);
                    s = s * __expf(m - nm) + __expf(t - nm);
                    m = nm;
                }
            }
#pragma unroll
            for (int d = 8; d <= 32; d <<= 1) {
                float mo = __shfl_xor(m, d), so = __shfl_xor(s, d);
                float nm = fmaxf(m, mo);
                s = s * __expf(m - nm) + so * __expf(mo - nm);
                m = nm;
            }
            float sinv = 1.0f / (s + 1e-16f);

#pragma unroll
            for (int i = 0; i < 8; ++i) {
                int b0 = i * 8;
                if (b0 >= deg) break;
                float alpha = (b0 + el < deg) ? __expf(vv[i] - m) * sinv : 0.f;
                sAl[wid][lane] = alpha;  // stats layout: [e&7]*8 + hd  (same-wave use)
#pragma unroll
                for (int j = 0; j < 8; ++j) {
                    int s0 = __shfl(ss[i], j * 8);
                    float xv = X[(size_t)s0 * 64 + lane];
                    float4 a01 = *(const float4*)&sAl[wid][j * 8];      // broadcast
                    float4 a23 = *(const float4*)&sAl[wid][j * 8 + 4];
                    acc[0] += a01.x * xv; acc[1] += a01.y * xv;
                    acc[2] += a01.z * xv; acc[3] += a01.w * xv;
                    acc[4] += a23.x * xv; acc[5] += a23.y * xv;
                    acc[6] += a23.z * xv; acc[7] += a23.w * xv;
                }
            }
            for (int b0 = 64; b0 < deg; b0 += 8) {
                int e = b0 + el;
                float alpha = 0.f; int src = 0;
                if (e < deg) {
                    src = csr[off + e];
                    float t = AL[(size_t)src * 16 + hd] + ald;
                    t = t > 0.f ? t : NEG_SLOPE * t;
                    alpha = __expf(t - m) * sinv;
                }
                sAl[wid][lane] = alpha;
#pragma unroll
                for (int j = 0; j < 8; ++j) {
                    int s0 = __shfl(src, j * 8);
                    float xv = X[(size_t)s0 * 64 + lane];
                    float4 a01 = *(const float4*)&sAl[wid][j * 8];
                    float4 a23 = *(const float4*)&sAl[wid][j * 8 + 4];
                    acc[0] += a01.x * xv; acc[1] += a01.y * xv;
                    acc[2] += a01.z * xv; acc[3] += a01.w * xv;
                    acc[4] += a23.x * xv; acc[5] += a23.y * xv;
                    acc[6] += a23.z * xv; acc[7] += a23.w * xv;
                }
            }
        }
#pragma unroll
        for (int r = 0; r < 8; ++r) {
            int chunk = r * 8 + (lane >> 3);
            sA[chunk * 128 + ((mrow + chunk) & 15) * 8 + (lane & 7)] = __float2bfloat16(acc[r]);
        }
    }
    __syncthreads();

    // ---- MFMA projection: waves 0..2 each one 16-col N-tile, K=512
    if (wid < 3) {
        f32x4 cacc = {0.f, 0.f, 0.f, 0.f};
        int grp = lane >> 4;
        int r16 = lane & 15;
#pragma unroll 4
        for (int ks = 0; ks < 16; ++ks) {
            int c = ks * 4 + grp;
            short8v av = *(const short8v*)&sA[c * 128 + ((r16 + c) & 15) * 8];
            short8v bv = *(const short8v*)&w2sw[(size_t)(c * 48 + wid * 16 + r16) * 8];
            cacc = __builtin_amdgcn_mfma_f32_16x16x32_bf16(av, bv, cacc, 0, 0, 0);
        }
#pragma unroll
        for (int jj = 0; jj < 4; ++jj)
            sC[grp * 4 + jj][wid * 16 + r16] = cacc[jj];
    }
    __syncthreads();

    // ---- epilogue: + skip, log_softmax over 40 outputs
    for (int p = 0; p < 4; ++p) {
        int mrow = wid * 4 + p;
        int n = blockIdx.x * 16 + mrow;
        if (n >= N) continue;
        float val = (lane < 40) ? SK[(size_t)n * 40 + lane] + sC[mrow][lane] * 0.125f : -INFINITY;
        float mx = val;
#pragma unroll
        for (int d = 32; d; d >>= 1) mx = fmaxf(mx, __shfl_xor(mx, d));
        float ex = (lane < 40) ? __expf(val - mx) : 0.f;
        float sm = ex;
#pragma unroll
        for (int d = 32; d; d >>= 1) sm += __shfl_xor(sm, d);
        if (lane < 40) out[(size_t)n * 40 + lane] = val - mx - logf(sm);
    }
}

// ---------------------------------------------------------------- launch
extern "C" void kernel_launch(void* const* d_in, const int* in_sizes, int n_in,
                              void* d_out, int out_size, void* d_ws, size_t ws_size,
                              hipStream_t stream) {
    const float* x   = (const float*)d_in[0];
    const int*   ei  = (const int*)d_in[1];
    const float* W0  = (const float*)d_in[2];
    const float* as0 = (const float*)d_in[3];
    const float* ad0 = (const float*)d_in[4];
    const float* b0  = (const float*)d_in[5];
    const float* sW0 = (const float*)d_in[6];
    const float* sb0 = (const float*)d_in[7];
    const float* W1  = (const float*)d_in[8];
    const float* as1 = (const float*)d_in[9];
    const float* ad1 = (const float*)d_in[10];
    const float* b1  = (const float*)d_in[11];
    const float* sW1 = (const float*)d_in[12];
    const float* sb1 = (const float*)d_in[13];
    const float* W2  = (const float*)d_in[14];
    const float* as2 = (const float*)d_in[15];
    const float* ad2 = (const float*)d_in[16];
    const float* b2  = (const float*)d_in[17];
    const float* sW2 = (const float*)d_in[18];
    const float* sb2 = (const float*)d_in[19];
    float* out = (float*)d_out;

    int N = in_sizes[0] / 128;
    int E = in_sizes[1] / 2;
    int ET = E + N;

    char* wsp = (char*)d_ws;
    size_t woff = 0;
    auto A = [&](size_t nbytes) -> void* {
        void* p = wsp + woff;
        woff = (woff + nbytes + 255) & ~(size_t)255;
        return p;
    };
    int* offs   = (int*)A((size_t)(N + 1) * 4);
    int* cur    = (int*)A((size_t)N * 4);
    int* deg    = (int*)A((size_t)N * 4);
    int* bsum   = (int*)A(4096);
    int* csr    = (int*)A((size_t)ET * 4);
    float* wt   = (float*)A(1024 * 4);
    __hip_bfloat16* w2sw = (__hip_bfloat16*)A(64 * 48 * 8 * 2);
    float* AL   = (float*)A((size_t)N * 16 * 4);
    float* H    = (float*)A((size_t)N * 64 * 4);
    float* S    = (float*)A((size_t)N * 64 * 4);
    float* T    = (float*)A((size_t)N * 64 * 4);
    (void)ws_size; (void)n_in; (void)out_size;

    // ---- CSR build
    k_initdeg<<<(N + 255) / 256, 256, 0, stream>>>(deg, N);
    k_count<<<(E + 255) / 256, 256, 0, stream>>>(ei, deg, E);
    int nb = (N + 1023) / 1024;
    k_scan_block<<<nb, 256, 0, stream>>>(deg, offs, bsum, N);
    k_scan_top<<<1, 1, 0, stream>>>(bsum, nb);
    k_scan_add<<<(N + 255) / 256, 256, 0, stream>>>(offs, bsum, N);
    k_initcur<<<(N + 255) / 256, 256, 0, stream>>>(cur, offs, N);
    k_scatter<<<(ET + 255) / 256, 256, 0, stream>>>(ei, cur, csr, E, ET);

    dim3 bG(16, 16);
    int gG = (N + 63) / 64;
    int gN4 = (N + 3) / 4;

    // ---- layer 0 (input x [N,128])
    k_gemm2<4><<<gG, bG, 0, stream>>>(x, W0, nullptr, nullptr, H, N, 128, 64);
    k_gemm2<4><<<gG, bG, 0, stream>>>(x, sW0, b0, sb0, S, N, 128, 64);
    k_al<<<(N * 16 + 255) / 256, 256, 0, stream>>>(H, as0, ad0, AL, N);
    k_fused<<<gN4, 256, 0, stream>>>(H, AL, offs, csr, S, N);   // S <- elu(S + gat) = x1

    // ---- layer 1 (input S [N,64])
    k_gemm2<4><<<gG, bG, 0, stream>>>(S, W1, nullptr, nullptr, H, N, 64, 64);
    k_gemm2<4><<<gG, bG, 0, stream>>>(S, sW1, b1, sb1, T, N, 64, 64);
    k_al<<<(N * 16 + 255) / 256, 256, 0, stream>>>(H, as1, ad1, AL, N);
    k_fused<<<gN4, 256, 0, stream>>>(H, AL, offs, csr, T, N);   // T <- x2

    // ---- layer 2 (input T [N,64])
    k_wt<<<4, 256, 0, stream>>>(W2, as2, ad2, wt);
    k_w2sw<<<96, 256, 0, stream>>>(W2, w2sw);
    k_gemm2<1><<<gG, bG, 0, stream>>>(T, wt, nullptr, nullptr, AL, N, 64, 16);
    k_gemm2<3><<<gG, bG, 0, stream>>>(T, sW2, b2, sb2, S, N, 64, 40);
    k_l2f<<<(N + 15) / 16, 256, 0, stream>>>(T, AL, S, w2sw, offs, csr, out, N);
}

// Round 6
// 775.479 us; speedup vs baseline: 11.2042x; 1.0433x over previous
//
#include <hip/hip_runtime.h>
#include <hip/hip_bf16.h>
#include <math.h>

#define HEADS 8
#define NEG_SLOPE 0.2f

typedef __attribute__((ext_vector_type(8))) short short8v;
typedef __attribute__((ext_vector_type(4))) float f32x4;

// ---------------------------------------------------------------- CSR build
__global__ void k_initdeg(int* __restrict__ deg, int N) {
    int i = blockIdx.x * 256 + threadIdx.x;
    if (i < N) deg[i] = 1;  // self-loop
}

__global__ void k_count(const int* __restrict__ ei, int* __restrict__ deg, int E) {
    int i = blockIdx.x * 256 + threadIdx.x;
    if (i < E) atomicAdd(&deg[ei[E + i]], 1);  // dst row
}

__global__ void k_scan_block(const int* __restrict__ deg, int* __restrict__ offs,
                             int* __restrict__ bsum, int N) {
    __shared__ int lds[256];
    int tid = threadIdx.x;
    int base = blockIdx.x * 1024 + tid * 4;
    int v0 = (base + 0 < N) ? deg[base + 0] : 0;
    int v1 = (base + 1 < N) ? deg[base + 1] : 0;
    int v2 = (base + 2 < N) ? deg[base + 2] : 0;
    int v3 = (base + 3 < N) ? deg[base + 3] : 0;
    int t01 = v0 + v1;
    int tot = t01 + v2 + v3;
    lds[tid] = tot;
    __syncthreads();
    for (int off = 1; off < 256; off <<= 1) {
        int x = 0;
        if (tid >= off) x = lds[tid - off];
        __syncthreads();
        lds[tid] += x;
        __syncthreads();
    }
    int ex = lds[tid] - tot;
    if (tid == 255) bsum[blockIdx.x] = lds[255];
    if (base + 0 < N) offs[base + 0] = ex;
    if (base + 1 < N) offs[base + 1] = ex + v0;
    if (base + 2 < N) offs[base + 2] = ex + t01;
    if (base + 3 < N) offs[base + 3] = ex + t01 + v2;
}

__global__ void k_scan_top(int* __restrict__ bsum, int nb) {
    if (threadIdx.x == 0 && blockIdx.x == 0) {
        int run = 0;
        for (int b = 0; b < nb; ++b) { int t = bsum[b]; bsum[b] = run; run += t; }
        bsum[nb] = run;
    }
}

__global__ void k_scan_add(int* __restrict__ offs, const int* __restrict__ bsum, int N) {
    int i = blockIdx.x * 256 + threadIdx.x;
    if (i < N) offs[i] += bsum[i >> 10];
    if (i == 0) offs[N] = bsum[(N + 1023) >> 10];
}

__global__ void k_initcur(int* __restrict__ cur, const int* __restrict__ offs, int N) {
    int i = blockIdx.x * 256 + threadIdx.x;
    if (i < N) cur[i] = offs[i];
}

__global__ void k_scatter(const int* __restrict__ ei, int* __restrict__ cur,
                          int* __restrict__ csr, int E, int ET) {
    int i = blockIdx.x * 256 + threadIdx.x;
    if (i >= ET) return;
    int s, d;
    if (i < E) { s = ei[i]; d = ei[E + i]; }
    else       { s = d = i - E; }
    int pos = atomicAdd(&cur[d], 1);
    csr[pos] = s;
}

// ---------------------------------------------------------------- register-blocked GEMM
// out[N,M] = X[N,K]@W[M,K]^T + b1 + b2.  block dim3(16,16); 64 rows/block.
template <int CPT>
__global__ __launch_bounds__(256) void k_gemm2(
    const float* __restrict__ X, const float* __restrict__ W,
    const float* __restrict__ bias1, const float* __restrict__ bias2,
    float* __restrict__ out, int N, int K, int M) {
    __shared__ float sW[CPT * 16][68];
    __shared__ float sX[64][68];
    int tx = threadIdx.x, ty = threadIdx.y;
    int tid = ty * 16 + tx;
    int r0 = blockIdx.x * 64;

    float acc[4][CPT];
#pragma unroll
    for (int jc = 0; jc < CPT; ++jc) {
        int col = tx + 16 * jc;
        float b = 0.f;
        if (col < M) {
            if (bias1) b += bias1[col];
            if (bias2) b += bias2[col];
        }
#pragma unroll
        for (int jr = 0; jr < 4; ++jr) acc[jr][jc] = b;
    }

    for (int k0 = 0; k0 < K; k0 += 64) {
        __syncthreads();
        for (int idx = tid; idx < CPT * 16 * 16; idx += 256) {
            int c = idx >> 4, kq = (idx & 15) * 4;
            float4 v = make_float4(0.f, 0.f, 0.f, 0.f);
            if (c < M) v = *(const float4*)&W[(size_t)c * K + k0 + kq];
            *(float4*)&sW[c][kq] = v;
        }
        for (int idx = tid; idx < 64 * 16; idx += 256) {
            int r = idx >> 4, kq = (idx & 15) * 4;
            int gr = r0 + r;
            float4 v = make_float4(0.f, 0.f, 0.f, 0.f);
            if (gr < N) v = *(const float4*)&X[(size_t)gr * K + k0 + kq];
            *(float4*)&sX[r][kq] = v;
        }
        __syncthreads();

        for (int k = 0; k < 64; k += 4) {
            float4 xr[4], wc[CPT];
#pragma unroll
            for (int jr = 0; jr < 4; ++jr) xr[jr] = *(const float4*)&sX[ty * 4 + jr][k];
#pragma unroll
            for (int jc = 0; jc < CPT; ++jc) wc[jc] = *(const float4*)&sW[tx + 16 * jc][k];
#pragma unroll
            for (int jc = 0; jc < CPT; ++jc)
#pragma unroll
                for (int jr = 0; jr < 4; ++jr)
                    acc[jr][jc] += wc[jc].x * xr[jr].x + wc[jc].y * xr[jr].y +
                                   wc[jc].z * xr[jr].z + wc[jc].w * xr[jr].w;
        }
    }

#pragma unroll
    for (int jr = 0; jr < 4; ++jr) {
        int gr = r0 + ty * 4 + jr;
        if (gr >= N) continue;
#pragma unroll
        for (int jc = 0; jc < CPT; ++jc) {
            int col = tx + 16 * jc;
            if (col < M) out[(size_t)gr * M + col] = acc[jr][jc];
        }
    }
}

// ---------------------------------------------------------------- attention logits for layers 0/1 (C=8)
__global__ void k_al(const float* __restrict__ H, const float* __restrict__ as_w,
                     const float* __restrict__ ad_w, float* __restrict__ AL, int N) {
    int t = blockIdx.x * 256 + threadIdx.x;
    int n = t >> 4;
    if (n >= N) return;
    int j = t & 15;
    int hd = j & 7;
    const float* a = (j < 8 ? as_w : ad_w) + hd * 8;
    const float* hp = H + (size_t)n * 64 + hd * 8;
    float sum = 0.f;
#pragma unroll
    for (int c = 0; c < 8; ++c) sum += a[c] * hp[c];
    AL[t] = sum;
}

// wt[j,k] = sum_c a[j][c] * W2[(hd*40+c)*64 + k]   (j<8: a_src, j>=8: a_dst)
__global__ void k_wt(const float* __restrict__ W2, const float* __restrict__ as2,
                     const float* __restrict__ ad2, float* __restrict__ wt) {
    int t = blockIdx.x * 256 + threadIdx.x;
    if (t >= 1024) return;
    int j = t >> 6, k = t & 63;
    int hd = j & 7;
    const float* a = (j < 8 ? as2 : ad2) + hd * 40;
    float sum = 0.f;
    for (int c = 0; c < 40; ++c) sum += a[c] * W2[(size_t)(hd * 40 + c) * 64 + k];
    wt[j * 64 + k] = sum;
}

// w2sw: bf16 W2T pre-swizzled for MFMA B-fragments.
__global__ void k_w2sw(const float* __restrict__ W2, __hip_bfloat16* __restrict__ w2sw) {
    int t = blockIdx.x * 256 + threadIdx.x;
    if (t >= 64 * 48 * 8) return;
    int j = t & 7;
    int rc = t >> 3;
    int col = rc % 48, c = rc / 48;
    int k = c * 8 + j;
    int hd = k >> 6, kk = k & 63;
    float v = (col < 40) ? W2[(size_t)(hd * 40 + col) * 64 + kk] : 0.f;
    w2sw[t] = __float2bfloat16(v);
}

// ---------------------------------------------------------------- layers 0/1: SINGLE-PASS flash softmax-aggregate + skip + ELU
// 1 wave/node. Per 8-edge block: AL-gathers and H-row-gathers issue together;
// running (m,s) per head updated via shfl_xor block reductions; acc rescaled.
__global__ __launch_bounds__(256) void k_fused(
    const float* __restrict__ H, const float* __restrict__ AL,
    const int* __restrict__ offs, const int* __restrict__ csr,
    float* __restrict__ S, int N) {
    int wid = threadIdx.x >> 6, lane = threadIdx.x & 63;
    int n = blockIdx.x * 4 + wid;
    if (n >= N) return;
    int off = offs[n], deg = offs[n + 1] - off;
    int el = lane >> 3, hd = lane & 7;
    int fhd = lane >> 3;  // feature-role head
    float ald = AL[(size_t)n * 16 + 8 + hd];

    // prologue prefetch of block 0's (src, logit)
    bool vc = el < deg;
    int src_c = vc ? csr[off + el] : 0;
    float v_c = -1e30f;
    if (vc) { float t = AL[(size_t)src_c * 16 + hd] + ald; v_c = t > 0.f ? t : NEG_SLOPE * t; }

    float m_run = -1e30f, s_run = 0.f, acc = 0.f;
    for (int b0 = 0; b0 < deg; b0 += 8) {
        // feature gathers for current block (issue ASAP)
        float hv[8];
#pragma unroll
        for (int j = 0; j < 8; ++j) {
            int sj = __shfl(src_c, j * 8);
            hv[j] = (b0 + j < deg) ? H[(size_t)sj * 64 + lane] : 0.f;
        }
        // prefetch next block's (src, logit) — hides csr->AL chain under this block
        int en = b0 + 8 + el;
        bool vn = en < deg;
        int src_n = vn ? csr[off + en] : 0;
        float v_n = -1e30f;
        if (vn) { float t = AL[(size_t)src_n * 16 + hd] + ald; v_n = t > 0.f ? t : NEG_SLOPE * t; }

        // block softmax update (stats layout)
        float mb = v_c;
#pragma unroll
        for (int d = 8; d <= 32; d <<= 1) mb = fmaxf(mb, __shfl_xor(mb, d));
        float mnew = fmaxf(m_run, mb);
        float expv = __expf(v_c - mnew);        // invalid lanes -> 0
        float sb = expv;
#pragma unroll
        for (int d = 8; d <= 32; d <<= 1) sb += __shfl_xor(sb, d);
        float f = __expf(m_run - mnew);         // first block -> 0
        s_run = s_run * f + sb;
        m_run = mnew;

        // accumulate (feature layout)
        acc *= __shfl(f, fhd);
#pragma unroll
        for (int j = 0; j < 8; ++j)
            acc += __shfl(expv, j * 8 + fhd) * hv[j];

        src_c = src_n; v_c = v_n;
    }
    float sf = __shfl(s_run, fhd);
    acc *= 1.0f / (sf + 1e-16f);
    float val = S[(size_t)n * 64 + lane] + acc;
    S[(size_t)n * 64 + lane] = val > 0.f ? val : expm1f(val);
}

// ---------------------------------------------------------------- layer 2: single-pass flash aggregate (8 heads) -> bf16 LDS -> MFMA vs w2sw
// block: 256 threads / 4 waves / 16 nodes
__global__ __launch_bounds__(256) void k_l2f(
    const float* __restrict__ X, const float* __restrict__ AL,
    const float* __restrict__ SK, const __hip_bfloat16* __restrict__ w2sw,
    const int* __restrict__ offs, const int* __restrict__ csr,
    float* __restrict__ out, int N) {
    __shared__ __hip_bfloat16 sA[64 * 16 * 8];  // [chunk][rot-row][8], 16 KB
    __shared__ float sC[16][48];                // 3 KB
    __shared__ float sW8[4][64];                // per-wave weight broadcast row, 1 KB
    int wid = threadIdx.x >> 6, lane = threadIdx.x & 63;
    int el = lane >> 3, hd = lane & 7;

    for (int p = 0; p < 4; ++p) {
        int mrow = wid * 4 + p;
        int n = blockIdx.x * 16 + mrow;
        float acc[8] = {0.f, 0.f, 0.f, 0.f, 0.f, 0.f, 0.f, 0.f};
        if (n < N) {
            int off = offs[n], deg = offs[n + 1] - off;
            float ald = AL[(size_t)n * 16 + 8 + hd];

            bool vc = el < deg;
            int src_c = vc ? csr[off + el] : 0;
            float v_c = -1e30f;
            if (vc) { float t = AL[(size_t)src_c * 16 + hd] + ald; v_c = t > 0.f ? t : NEG_SLOPE * t; }

            float m_run = -1e30f, s_run = 0.f;
            for (int b0 = 0; b0 < deg; b0 += 8) {
                float xv[8];
#pragma unroll
                for (int j = 0; j < 8; ++j) {
                    int sj = __shfl(src_c, j * 8);
                    xv[j] = (b0 + j < deg) ? X[(size_t)sj * 64 + lane] : 0.f;
                }
                int en = b0 + 8 + el;
                bool vn = en < deg;
                int src_n = vn ? csr[off + en] : 0;
                float v_n = -1e30f;
                if (vn) { float t = AL[(size_t)src_n * 16 + hd] + ald; v_n = t > 0.f ? t : NEG_SLOPE * t; }

                float mb = v_c;
#pragma unroll
                for (int d = 8; d <= 32; d <<= 1) mb = fmaxf(mb, __shfl_xor(mb, d));
                float mnew = fmaxf(m_run, mb);
                float expv = __expf(v_c - mnew);
                float sb = expv;
#pragma unroll
                for (int d = 8; d <= 32; d <<= 1) sb += __shfl_xor(sb, d);
                float f = __expf(m_run - mnew);
                s_run = s_run * f + sb;
                m_run = mnew;

                sW8[wid][lane] = expv;   // stats layout [e&7]*8+hd, same-wave consume
#pragma unroll
                for (int r = 0; r < 8; ++r) acc[r] *= __shfl(f, r);
#pragma unroll
                for (int j = 0; j < 8; j += 2) {
                    float4 wa0 = *(const float4*)&sW8[wid][j * 8];
                    float4 wa1 = *(const float4*)&sW8[wid][j * 8 + 4];
                    float4 wb0 = *(const float4*)&sW8[wid][j * 8 + 8];
                    float4 wb1 = *(const float4*)&sW8[wid][j * 8 + 12];
                    acc[0] += wa0.x * xv[j] + wb0.x * xv[j + 1];
                    acc[1] += wa0.y * xv[j] + wb0.y * xv[j + 1];
                    acc[2] += wa0.z * xv[j] + wb0.z * xv[j + 1];
                    acc[3] += wa0.w * xv[j] + wb0.w * xv[j + 1];
                    acc[4] += wa1.x * xv[j] + wb1.x * xv[j + 1];
                    acc[5] += wa1.y * xv[j] + wb1.y * xv[j + 1];
                    acc[6] += wa1.z * xv[j] + wb1.z * xv[j + 1];
                    acc[7] += wa1.w * xv[j] + wb1.w * xv[j + 1];
                }
                src_c = src_n; v_c = v_n;
            }
            float sinv = 1.0f / (s_run + 1e-16f);
#pragma unroll
            for (int r = 0; r < 8; ++r) acc[r] *= __shfl(sinv, r);
        }
#pragma unroll
        for (int r = 0; r < 8; ++r) {
            int chunk = r * 8 + (lane >> 3);
            sA[chunk * 128 + ((mrow + chunk) & 15) * 8 + (lane & 7)] = __float2bfloat16(acc[r]);
        }
    }
    __syncthreads();

    // ---- MFMA projection: waves 0..2 each one 16-col N-tile, K=512
    if (wid < 3) {
        f32x4 cacc = {0.f, 0.f, 0.f, 0.f};
        int grp = lane >> 4;
        int r16 = lane & 15;
#pragma unroll 4
        for (int ks = 0; ks < 16; ++ks) {
            int c = ks * 4 + grp;
            short8v av = *(const short8v*)&sA[c * 128 + ((r16 + c) & 15) * 8];
            short8v bv = *(const short8v*)&w2sw[(size_t)(c * 48 + wid * 16 + r16) * 8];
            cacc = __builtin_amdgcn_mfma_f32_16x16x32_bf16(av, bv, cacc, 0, 0, 0);
        }
#pragma unroll
        for (int jj = 0; jj < 4; ++jj)
            sC[grp * 4 + jj][wid * 16 + r16] = cacc[jj];
    }
    __syncthreads();

    // ---- epilogue: + skip, log_softmax over 40 outputs
    for (int p = 0; p < 4; ++p) {
        int mrow = wid * 4 + p;
        int n = blockIdx.x * 16 + mrow;
        if (n >= N) continue;
        float val = (lane < 40) ? SK[(size_t)n * 40 + lane] + sC[mrow][lane] * 0.125f : -INFINITY;
        float mx = val;
#pragma unroll
        for (int d = 32; d; d >>= 1) mx = fmaxf(mx, __shfl_xor(mx, d));
        float ex = (lane < 40) ? __expf(val - mx) : 0.f;
        float sm = ex;
#pragma unroll
        for (int d = 32; d; d >>= 1) sm += __shfl_xor(sm, d);
        if (lane < 40) out[(size_t)n * 40 + lane] = val - mx - logf(sm);
    }
}

// ---------------------------------------------------------------- launch
extern "C" void kernel_launch(void* const* d_in, const int* in_sizes, int n_in,
                              void* d_out, int out_size, void* d_ws, size_t ws_size,
                              hipStream_t stream) {
    const float* x   = (const float*)d_in[0];
    const int*   ei  = (const int*)d_in[1];
    const float* W0  = (const float*)d_in[2];
    const float* as0 = (const float*)d_in[3];
    const float* ad0 = (const float*)d_in[4];
    const float* b0  = (const float*)d_in[5];
    const float* sW0 = (const float*)d_in[6];
    const float* sb0 = (const float*)d_in[7];
    const float* W1  = (const float*)d_in[8];
    const float* as1 = (const float*)d_in[9];
    const float* ad1 = (const float*)d_in[10];
    const float* b1  = (const float*)d_in[11];
    const float* sW1 = (const float*)d_in[12];
    const float* sb1 = (const float*)d_in[13];
    const float* W2  = (const float*)d_in[14];
    const float* as2 = (const float*)d_in[15];
    const float* ad2 = (const float*)d_in[16];
    const float* b2  = (const float*)d_in[17];
    const float* sW2 = (const float*)d_in[18];
    const float* sb2 = (const float*)d_in[19];
    float* out = (float*)d_out;

    int N = in_sizes[0] / 128;
    int E = in_sizes[1] / 2;
    int ET = E + N;

    char* wsp = (char*)d_ws;
    size_t woff = 0;
    auto A = [&](size_t nbytes) -> void* {
        void* p = wsp + woff;
        woff = (woff + nbytes + 255) & ~(size_t)255;
        return p;
    };
    int* offs   = (int*)A((size_t)(N + 1) * 4);
    int* cur    = (int*)A((size_t)N * 4);
    int* deg    = (int*)A((size_t)N * 4);
    int* bsum   = (int*)A(4096);
    int* csr    = (int*)A((size_t)ET * 4);
    float* wt   = (float*)A(1024 * 4);
    __hip_bfloat16* w2sw = (__hip_bfloat16*)A(64 * 48 * 8 * 2);
    float* AL   = (float*)A((size_t)N * 16 * 4);
    float* H    = (float*)A((size_t)N * 64 * 4);
    float* S    = (float*)A((size_t)N * 64 * 4);
    float* T    = (float*)A((size_t)N * 64 * 4);
    (void)ws_size; (void)n_in; (void)out_size;

    // ---- CSR build
    k_initdeg<<<(N + 255) / 256, 256, 0, stream>>>(deg, N);
    k_count<<<(E + 255) / 256, 256, 0, stream>>>(ei, deg, E);
    int nb = (N + 1023) / 1024;
    k_scan_block<<<nb, 256, 0, stream>>>(deg, offs, bsum, N);
    k_scan_top<<<1, 1, 0, stream>>>(bsum, nb);
    k_scan_add<<<(N + 255) / 256, 256, 0, stream>>>(offs, bsum, N);
    k_initcur<<<(N + 255) / 256, 256, 0, stream>>>(cur, offs, N);
    k_scatter<<<(ET + 255) / 256, 256, 0, stream>>>(ei, cur, csr, E, ET);

    dim3 bG(16, 16);
    int gG = (N + 63) / 64;
    int gN4 = (N + 3) / 4;

    // ---- layer 0 (input x [N,128])
    k_gemm2<4><<<gG, bG, 0, stream>>>(x, W0, nullptr, nullptr, H, N, 128, 64);
    k_gemm2<4><<<gG, bG, 0, stream>>>(x, sW0, b0, sb0, S, N, 128, 64);
    k_al<<<(N * 16 + 255) / 256, 256, 0, stream>>>(H, as0, ad0, AL, N);
    k_fused<<<gN4, 256, 0, stream>>>(H, AL, offs, csr, S, N);   // S <- elu(S + gat) = x1

    // ---- layer 1 (input S [N,64])
    k_gemm2<4><<<gG, bG, 0, stream>>>(S, W1, nullptr, nullptr, H, N, 64, 64);
    k_gemm2<4><<<gG, bG, 0, stream>>>(S, sW1, b1, sb1, T, N, 64, 64);
    k_al<<<(N * 16 + 255) / 256, 256, 0, stream>>>(H, as1, ad1, AL, N);
    k_fused<<<gN4, 256, 0, stream>>>(H, AL, offs, csr, T, N);   // T <- x2

    // ---- layer 2 (input T [N,64])
    k_wt<<<4, 256, 0, stream>>>(W2, as2, ad2, wt);
    k_w2sw<<<96, 256, 0, stream>>>(W2, w2sw);
    k_gemm2<1><<<gG, bG, 0, stream>>>(T, wt, nullptr, nullptr, AL, N, 64, 16);
    k_gemm2<3><<<gG, bG, 0, stream>>>(T, sW2, b2, sb2, S, N, 64, 40);
    k_l2f<<<(N + 15) / 16, 256, 0, stream>>>(T, AL, S, w2sw, offs, csr, out, N);
}

// Round 7
// 658.759 us; speedup vs baseline: 13.1893x; 1.1772x over previous
//
#include <hip/hip_runtime.h>
#include <hip/hip_bf16.h>
#include <math.h>

#define HEADS 8
#define NEG_SLOPE 0.2f

typedef __attribute__((ext_vector_type(8))) short short8v;
typedef __attribute__((ext_vector_type(4))) float f32x4;

__device__ __forceinline__ float bf2f(unsigned short u) {
    return __uint_as_float(((unsigned int)u) << 16);
}
__device__ __forceinline__ unsigned short f2bf(float f) {
    __hip_bfloat16 h = __float2bfloat16(f);
    union { __hip_bfloat16 h; unsigned short u; } c; c.h = h; return c.u;
}

// ---------------------------------------------------------------- CSR build
__global__ void k_initdeg(int* __restrict__ deg, int N) {
    int i = blockIdx.x * 256 + threadIdx.x;
    if (i < N) deg[i] = 1;  // self-loop
}

__global__ void k_count(const int* __restrict__ ei, int* __restrict__ deg, int E) {
    int i = blockIdx.x * 256 + threadIdx.x;
    if (i < E) atomicAdd(&deg[ei[E + i]], 1);  // dst row
}

__global__ void k_scan_block(const int* __restrict__ deg, int* __restrict__ offs,
                             int* __restrict__ bsum, int N) {
    __shared__ int lds[256];
    int tid = threadIdx.x;
    int base = blockIdx.x * 1024 + tid * 4;
    int v0 = (base + 0 < N) ? deg[base + 0] : 0;
    int v1 = (base + 1 < N) ? deg[base + 1] : 0;
    int v2 = (base + 2 < N) ? deg[base + 2] : 0;
    int v3 = (base + 3 < N) ? deg[base + 3] : 0;
    int t01 = v0 + v1;
    int tot = t01 + v2 + v3;
    lds[tid] = tot;
    __syncthreads();
    for (int off = 1; off < 256; off <<= 1) {
        int x = 0;
        if (tid >= off) x = lds[tid - off];
        __syncthreads();
        lds[tid] += x;
        __syncthreads();
    }
    int ex = lds[tid] - tot;
    if (tid == 255) bsum[blockIdx.x] = lds[255];
    if (base + 0 < N) offs[base + 0] = ex;
    if (base + 1 < N) offs[base + 1] = ex + v0;
    if (base + 2 < N) offs[base + 2] = ex + t01;
    if (base + 3 < N) offs[base + 3] = ex + t01 + v2;
}

__global__ void k_scan_top(int* __restrict__ bsum, int nb) {
    if (threadIdx.x == 0 && blockIdx.x == 0) {
        int run = 0;
        for (int b = 0; b < nb; ++b) { int t = bsum[b]; bsum[b] = run; run += t; }
        bsum[nb] = run;
    }
}

__global__ void k_scan_add(int* __restrict__ offs, const int* __restrict__ bsum, int N) {
    int i = blockIdx.x * 256 + threadIdx.x;
    if (i < N) offs[i] += bsum[i >> 10];
    if (i == 0) offs[N] = bsum[(N + 1023) >> 10];
}

__global__ void k_initcur(int* __restrict__ cur, const int* __restrict__ offs, int N) {
    int i = blockIdx.x * 256 + threadIdx.x;
    if (i < N) cur[i] = offs[i];
}

__global__ void k_scatter(const int* __restrict__ ei, int* __restrict__ cur,
                          int* __restrict__ csr, int E, int ET) {
    int i = blockIdx.x * 256 + threadIdx.x;
    if (i >= ET) return;
    int s, d;
    if (i < E) { s = ei[i]; d = ei[E + i]; }
    else       { s = d = i - E; }
    int pos = atomicAdd(&cur[d], 1);
    csr[pos] = s;
}

// ---------------------------------------------------------------- fp32 -> bf16 mirror
__global__ void k_tobf(const float* __restrict__ T, unsigned short* __restrict__ Tb, int total4) {
    int i = blockIdx.x * 256 + threadIdx.x;
    if (i >= total4) return;
    float4 v = *(const float4*)&T[(size_t)i * 4];
    ushort4 o;
    o.x = f2bf(v.x); o.y = f2bf(v.y); o.z = f2bf(v.z); o.w = f2bf(v.w);
    *(ushort4*)&Tb[(size_t)i * 4] = o;
}

// ---------------------------------------------------------------- register-blocked GEMM
// out[N,M] = X[N,K]@W[M,K]^T + b1 + b2.  block dim3(16,16); 64 rows/block.
// OMODE: 0 fp32 only, 1 bf16 only, 2 both.
template <int CPT, int OMODE>
__global__ __launch_bounds__(256) void k_gemm2(
    const float* __restrict__ X, const float* __restrict__ W,
    const float* __restrict__ bias1, const float* __restrict__ bias2,
    float* __restrict__ out, unsigned short* __restrict__ outb, int N, int K, int M) {
    __shared__ float sW[CPT * 16][68];
    __shared__ float sX[64][68];
    int tx = threadIdx.x, ty = threadIdx.y;
    int tid = ty * 16 + tx;
    int r0 = blockIdx.x * 64;

    float acc[4][CPT];
#pragma unroll
    for (int jc = 0; jc < CPT; ++jc) {
        int col = tx + 16 * jc;
        float b = 0.f;
        if (col < M) {
            if (bias1) b += bias1[col];
            if (bias2) b += bias2[col];
        }
#pragma unroll
        for (int jr = 0; jr < 4; ++jr) acc[jr][jc] = b;
    }

    for (int k0 = 0; k0 < K; k0 += 64) {
        __syncthreads();
        for (int idx = tid; idx < CPT * 16 * 16; idx += 256) {
            int c = idx >> 4, kq = (idx & 15) * 4;
            float4 v = make_float4(0.f, 0.f, 0.f, 0.f);
            if (c < M) v = *(const float4*)&W[(size_t)c * K + k0 + kq];
            *(float4*)&sW[c][kq] = v;
        }
        for (int idx = tid; idx < 64 * 16; idx += 256) {
            int r = idx >> 4, kq = (idx & 15) * 4;
            int gr = r0 + r;
            float4 v = make_float4(0.f, 0.f, 0.f, 0.f);
            if (gr < N) v = *(const float4*)&X[(size_t)gr * K + k0 + kq];
            *(float4*)&sX[r][kq] = v;
        }
        __syncthreads();

        for (int k = 0; k < 64; k += 4) {
            float4 xr[4], wc[CPT];
#pragma unroll
            for (int jr = 0; jr < 4; ++jr) xr[jr] = *(const float4*)&sX[ty * 4 + jr][k];
#pragma unroll
            for (int jc = 0; jc < CPT; ++jc) wc[jc] = *(const float4*)&sW[tx + 16 * jc][k];
#pragma unroll
            for (int jc = 0; jc < CPT; ++jc)
#pragma unroll
                for (int jr = 0; jr < 4; ++jr)
                    acc[jr][jc] += wc[jc].x * xr[jr].x + wc[jc].y * xr[jr].y +
                                   wc[jc].z * xr[jr].z + wc[jc].w * xr[jr].w;
        }
    }

#pragma unroll
    for (int jr = 0; jr < 4; ++jr) {
        int gr = r0 + ty * 4 + jr;
        if (gr >= N) continue;
#pragma unroll
        for (int jc = 0; jc < CPT; ++jc) {
            int col = tx + 16 * jc;
            if (col < M) {
                if (OMODE != 1) out[(size_t)gr * M + col] = acc[jr][jc];
                if (OMODE != 0) outb[(size_t)gr * M + col] = f2bf(acc[jr][jc]);
            }
        }
    }
}

// ---------------------------------------------------------------- attention logits for layers 0/1 (C=8), fp32 H
__global__ void k_al(const float* __restrict__ H, const float* __restrict__ as_w,
                     const float* __restrict__ ad_w, float* __restrict__ AL, int N) {
    int t = blockIdx.x * 256 + threadIdx.x;
    int n = t >> 4;
    if (n >= N) return;
    int j = t & 15;
    int hd = j & 7;
    const float* a = (j < 8 ? as_w : ad_w) + hd * 8;
    const float* hp = H + (size_t)n * 64 + hd * 8;
    float sum = 0.f;
#pragma unroll
    for (int c = 0; c < 8; ++c) sum += a[c] * hp[c];
    AL[t] = sum;
}

// wt[j,k] = sum_c a[j][c] * W2[(hd*40+c)*64 + k]   (j<8: a_src, j>=8: a_dst)
__global__ void k_wt(const float* __restrict__ W2, const float* __restrict__ as2,
                     const float* __restrict__ ad2, float* __restrict__ wt) {
    int t = blockIdx.x * 256 + threadIdx.x;
    if (t >= 1024) return;
    int j = t >> 6, k = t & 63;
    int hd = j & 7;
    const float* a = (j < 8 ? as2 : ad2) + hd * 40;
    float sum = 0.f;
    for (int c = 0; c < 40; ++c) sum += a[c] * W2[(size_t)(hd * 40 + c) * 64 + k];
    wt[j * 64 + k] = sum;
}

// w2sw: bf16 W2T pre-swizzled for MFMA B-fragments.
__global__ void k_w2sw(const float* __restrict__ W2, __hip_bfloat16* __restrict__ w2sw) {
    int t = blockIdx.x * 256 + threadIdx.x;
    if (t >= 64 * 48 * 8) return;
    int j = t & 7;
    int rc = t >> 3;
    int col = rc % 48, c = rc / 48;
    int k = c * 8 + j;
    int hd = k >> 6, kk = k & 63;
    float v = (col < 40) ? W2[(size_t)(hd * 40 + col) * 64 + kk] : 0.f;
    w2sw[t] = __float2bfloat16(v);
}

// ---------------------------------------------------------------- layers 0/1: flash softmax-aggregate, bf16 rows, paired-dim layout
// 1 wave/node. Lane = es*32 + dp: edge-parity es, dim-pair dp (dims 2dp,2dp+1).
// Per 8-edge block: 4 dword gathers (2 rows/instr), stats in el*8+hd layout.
__global__ __launch_bounds__(256, 8) void k_fused(
    const unsigned short* __restrict__ Hb, const float* __restrict__ AL,
    const int* __restrict__ offs, const int* __restrict__ csr,
    float* __restrict__ S, int N) {
    int wid = threadIdx.x >> 6, lane = threadIdx.x & 63;
    int n = blockIdx.x * 4 + wid;
    if (n >= N) return;
    int off = offs[n], deg = offs[n + 1] - off;
    int el = lane >> 3, hd = lane & 7;
    int dp = lane & 31, es = lane >> 5;
    int hp = dp >> 2;  // head of dims (2dp,2dp+1)
    float ald = AL[(size_t)n * 16 + 8 + hd];

    bool vc = el < deg;
    int src_c = vc ? csr[off + el] : 0;
    float v_c = -1e30f;
    if (vc) { float t = AL[(size_t)src_c * 16 + hd] + ald; v_c = t > 0.f ? t : NEG_SLOPE * t; }

    float m_run = -1e30f, s_run = 0.f;
    float ax = 0.f, ay = 0.f;
    for (int b0 = 0; b0 < deg; b0 += 8) {
        // 4 paired row-gathers (rows b0+2j+es)
        unsigned int hv[4];
#pragma unroll
        for (int j = 0; j < 4; ++j) {
            int sj = __shfl(src_c, (2 * j + es) * 8);
            hv[j] = *(const unsigned int*)&Hb[(size_t)sj * 64 + 2 * dp];
        }
        // prefetch next block stats
        int en = b0 + 8 + el;
        bool vn = en < deg;
        int src_n = vn ? csr[off + en] : 0;
        float v_n = -1e30f;
        if (vn) { float t = AL[(size_t)src_n * 16 + hd] + ald; v_n = t > 0.f ? t : NEG_SLOPE * t; }

        // block softmax (stats layout)
        float mb = v_c;
#pragma unroll
        for (int d = 8; d <= 32; d <<= 1) mb = fmaxf(mb, __shfl_xor(mb, d));
        float mnew = fmaxf(m_run, mb);
        float expv = __expf(v_c - mnew);
        float sb = expv;
#pragma unroll
        for (int d = 8; d <= 32; d <<= 1) sb += __shfl_xor(sb, d);
        float f = __expf(m_run - mnew);
        s_run = s_run * f + sb;
        m_run = mnew;

        float fh = __shfl(f, hp);
        ax *= fh; ay *= fh;
#pragma unroll
        for (int j = 0; j < 4; ++j) {
            float a = __shfl(expv, (2 * j + es) * 8 + hp);
            unsigned int u = hv[j];
            ax += a * bf2f((unsigned short)(u & 0xffff));
            ay += a * bf2f((unsigned short)(u >> 16));
        }
        src_c = src_n; v_c = v_n;
    }
    float sf = __shfl(s_run, hp);
    float inv = 1.0f / (sf + 1e-16f);
    ax *= inv; ay *= inv;
    ax += __shfl_xor(ax, 32);
    ay += __shfl_xor(ay, 32);
    if (es == 0) {
        float2 sk = *(const float2*)&S[(size_t)n * 64 + 2 * dp];
        float vx = sk.x + ax, vy = sk.y + ay;
        vx = vx > 0.f ? vx : expm1f(vx);
        vy = vy > 0.f ? vy : expm1f(vy);
        *(float2*)&S[(size_t)n * 64 + 2 * dp] = make_float2(vx, vy);
    }
}

// ---------------------------------------------------------------- layer 2: flash aggregate, bf16 rows, head-split layout -> bf16 LDS -> MFMA
// Lane = eh*32 + dp: head-half eh (heads 4eh..4eh+3), dim-pair dp.
__global__ __launch_bounds__(256, 8) void k_l2f(
    const unsigned short* __restrict__ Xb, const float* __restrict__ AL,
    const float* __restrict__ SK, const __hip_bfloat16* __restrict__ w2sw,
    const int* __restrict__ offs, const int* __restrict__ csr,
    float* __restrict__ out, int N) {
    __shared__ __hip_bfloat16 sA[64 * 16 * 8];  // [chunk][rot-row][8], 16 KB
    __shared__ float sC[16][48];                // 3 KB
    __shared__ float sW8[4][64];                // per-wave alpha row, 1 KB
    int wid = threadIdx.x >> 6, lane = threadIdx.x & 63;
    int el = lane >> 3, hd = lane & 7;
    int dp = lane & 31, eh = lane >> 5;

#pragma unroll 1
    for (int p = 0; p < 4; ++p) {
        int mrow = wid * 4 + p;
        int n = blockIdx.x * 16 + mrow;
        float2 acc[4];
#pragma unroll
        for (int h2 = 0; h2 < 4; ++h2) acc[h2] = make_float2(0.f, 0.f);
        float s_fin[4] = {1.f, 1.f, 1.f, 1.f};
        if (n < N) {
            int off = offs[n], deg = offs[n + 1] - off;
            float ald = AL[(size_t)n * 16 + 8 + hd];

            bool vc = el < deg;
            int src_c = vc ? csr[off + el] : 0;
            float v_c = -1e30f;
            if (vc) { float t = AL[(size_t)src_c * 16 + hd] + ald; v_c = t > 0.f ? t : NEG_SLOPE * t; }

            float m_run = -1e30f, s_run = 0.f;
#pragma unroll 1
            for (int b0 = 0; b0 < deg; b0 += 8) {
                // first half rows 0..3 (each dword: dims 2dp,2dp+1; lanes l/l+32 same addr)
                unsigned int xv0[4];
#pragma unroll
                for (int j = 0; j < 4; ++j) {
                    int sj = __shfl(src_c, j * 8);
                    xv0[j] = *(const unsigned int*)&Xb[(size_t)sj * 64 + 2 * dp];
                }
                // prefetch next block stats
                int en = b0 + 8 + el;
                bool vn = en < deg;
                int src_n = vn ? csr[off + en] : 0;
                float v_n = -1e30f;
                if (vn) { float t = AL[(size_t)src_n * 16 + hd] + ald; v_n = t > 0.f ? t : NEG_SLOPE * t; }

                float mb = v_c;
#pragma unroll
                for (int d = 8; d <= 32; d <<= 1) mb = fmaxf(mb, __shfl_xor(mb, d));
                float mnew = fmaxf(m_run, mb);
                float expv = __expf(v_c - mnew);
                float sb = expv;
#pragma unroll
                for (int d = 8; d <= 32; d <<= 1) sb += __shfl_xor(sb, d);
                float f = __expf(m_run - mnew);
                s_run = s_run * f + sb;
                m_run = mnew;

                sW8[wid][lane] = expv;  // stats layout [e&7]*8+hd, same-wave consume
#pragma unroll
                for (int h2 = 0; h2 < 4; ++h2) {
                    float ff = __shfl(f, 4 * eh + h2);
                    acc[h2].x *= ff; acc[h2].y *= ff;
                }
#pragma unroll
                for (int j = 0; j < 4; ++j) {
                    float4 a4 = *(const float4*)&sW8[wid][j * 8 + 4 * eh];
                    float hx = bf2f((unsigned short)(xv0[j] & 0xffff));
                    float hy = bf2f((unsigned short)(xv0[j] >> 16));
                    acc[0].x += a4.x * hx; acc[0].y += a4.x * hy;
                    acc[1].x += a4.y * hx; acc[1].y += a4.y * hy;
                    acc[2].x += a4.z * hx; acc[2].y += a4.z * hy;
                    acc[3].x += a4.w * hx; acc[3].y += a4.w * hy;
                }
                // second half rows 4..7
#pragma unroll
                for (int j = 0; j < 4; ++j) {
                    int sj = __shfl(src_c, (j + 4) * 8);
                    xv0[j] = *(const unsigned int*)&Xb[(size_t)sj * 64 + 2 * dp];
                }
#pragma unroll
                for (int j = 0; j < 4; ++j) {
                    float4 a4 = *(const float4*)&sW8[wid][(j + 4) * 8 + 4 * eh];
                    float hx = bf2f((unsigned short)(xv0[j] & 0xffff));
                    float hy = bf2f((unsigned short)(xv0[j] >> 16));
                    acc[0].x += a4.x * hx; acc[0].y += a4.x * hy;
                    acc[1].x += a4.y * hx; acc[1].y += a4.y * hy;
                    acc[2].x += a4.z * hx; acc[2].y += a4.z * hy;
                    acc[3].x += a4.w * hx; acc[3].y += a4.w * hy;
                }
                src_c = src_n; v_c = v_n;
            }
#pragma unroll
            for (int h2 = 0; h2 < 4; ++h2) {
                float sv = __shfl(s_run, 4 * eh + h2);
                float iv = 1.0f / (sv + 1e-16f);
                acc[h2].x *= iv; acc[h2].y *= iv;
            }
        }
        // A[mrow][K]: K=(4eh+h2)*64+2dp; chunk=K>>3; rot row (mrow+chunk)&15
#pragma unroll
        for (int h2 = 0; h2 < 4; ++h2) {
            int K0 = (4 * eh + h2) * 64 + 2 * dp;
            int chunk = K0 >> 3, pos = K0 & 7;
            ushort2 w;
            w.x = f2bf(acc[h2].x); w.y = f2bf(acc[h2].y);
            *(ushort2*)&sA[chunk * 128 + ((mrow + chunk) & 15) * 8 + pos] = w;
        }
    }
    __syncthreads();

    // ---- MFMA projection: waves 0..2 each one 16-col N-tile, K=512
    if (wid < 3) {
        f32x4 cacc = {0.f, 0.f, 0.f, 0.f};
        int grp = lane >> 4;
        int r16 = lane & 15;
#pragma unroll 4
        for (int ks = 0; ks < 16; ++ks) {
            int c = ks * 4 + grp;
            short8v av = *(const short8v*)&sA[c * 128 + ((r16 + c) & 15) * 8];
            short8v bv = *(const short8v*)&w2sw[(size_t)(c * 48 + wid * 16 + r16) * 8];
            cacc = __builtin_amdgcn_mfma_f32_16x16x32_bf16(av, bv, cacc, 0, 0, 0);
        }
#pragma unroll
        for (int jj = 0; jj < 4; ++jj)
            sC[grp * 4 + jj][wid * 16 + r16] = cacc[jj];
    }
    __syncthreads();

    // ---- epilogue: + skip, log_softmax over 40 outputs
    for (int p = 0; p < 4; ++p) {
        int mrow = wid * 4 + p;
        int n = blockIdx.x * 16 + mrow;
        if (n >= N) continue;
        float val = (lane < 40) ? SK[(size_t)n * 40 + lane] + sC[mrow][lane] * 0.125f : -INFINITY;
        float mx = val;
#pragma unroll
        for (int d = 32; d; d >>= 1) mx = fmaxf(mx, __shfl_xor(mx, d));
        float ex = (lane < 40) ? __expf(val - mx) : 0.f;
        float sm = ex;
#pragma unroll
        for (int d = 32; d; d >>= 1) sm += __shfl_xor(sm, d);
        if (lane < 40) out[(size_t)n * 40 + lane] = val - mx - logf(sm);
    }
}

// ---------------------------------------------------------------- launch
extern "C" void kernel_launch(void* const* d_in, const int* in_sizes, int n_in,
                              void* d_out, int out_size, void* d_ws, size_t ws_size,
                              hipStream_t stream) {
    const float* x   = (const float*)d_in[0];
    const int*   ei  = (const int*)d_in[1];
    const float* W0  = (const float*)d_in[2];
    const float* as0 = (const float*)d_in[3];
    const float* ad0 = (const float*)d_in[4];
    const float* b0  = (const float*)d_in[5];
    const float* sW0 = (const float*)d_in[6];
    const float* sb0 = (const float*)d_in[7];
    const float* W1  = (const float*)d_in[8];
    const float* as1 = (const float*)d_in[9];
    const float* ad1 = (const float*)d_in[10];
    const float* b1  = (const float*)d_in[11];
    const float* sW1 = (const float*)d_in[12];
    const float* sb1 = (const float*)d_in[13];
    const float* W2  = (const float*)d_in[14];
    const float* as2 = (const float*)d_in[15];
    const float* ad2 = (const float*)d_in[16];
    const float* b2  = (const float*)d_in[17];
    const float* sW2 = (const float*)d_in[18];
    const float* sb2 = (const float*)d_in[19];
    float* out = (float*)d_out;

    int N = in_sizes[0] / 128;
    int E = in_sizes[1] / 2;
    int ET = E + N;

    char* wsp = (char*)d_ws;
    size_t woff = 0;
    auto A = [&](size_t nbytes) -> void* {
        void* p = wsp + woff;
        woff = (woff + nbytes + 255) & ~(size_t)255;
        return p;
    };
    int* offs   = (int*)A((size_t)(N + 1) * 4);
    int* cur    = (int*)A((size_t)N * 4);
    int* deg    = (int*)A((size_t)N * 4);
    int* bsum   = (int*)A(4096);
    int* csr    = (int*)A((size_t)ET * 4);
    float* wt   = (float*)A(1024 * 4);
    __hip_bfloat16* w2sw = (__hip_bfloat16*)A(64 * 48 * 8 * 2);
    float* AL   = (float*)A((size_t)N * 16 * 4);
    float* H    = (float*)A((size_t)N * 64 * 4);
    float* S    = (float*)A((size_t)N * 64 * 4);
    float* T    = (float*)A((size_t)N * 64 * 4);
    unsigned short* Hb = (unsigned short*)A((size_t)N * 64 * 2);
    unsigned short* Tb = (unsigned short*)A((size_t)N * 64 * 2);
    (void)ws_size; (void)n_in; (void)out_size;

    // ---- CSR build
    k_initdeg<<<(N + 255) / 256, 256, 0, stream>>>(deg, N);
    k_count<<<(E + 255) / 256, 256, 0, stream>>>(ei, deg, E);
    int nb = (N + 1023) / 1024;
    k_scan_block<<<nb, 256, 0, stream>>>(deg, offs, bsum, N);
    k_scan_top<<<1, 1, 0, stream>>>(bsum, nb);
    k_scan_add<<<(N + 255) / 256, 256, 0, stream>>>(offs, bsum, N);
    k_initcur<<<(N + 255) / 256, 256, 0, stream>>>(cur, offs, N);
    k_scatter<<<(ET + 255) / 256, 256, 0, stream>>>(ei, cur, csr, E, ET);

    dim3 bG(16, 16);
    int gG = (N + 63) / 64;
    int gN4 = (N + 3) / 4;
    int gBF = (N * 16 + 255) / 256;  // N*64/4 threads

    // ---- layer 0 (input x [N,128])
    k_gemm2<4, 2><<<gG, bG, 0, stream>>>(x, W0, nullptr, nullptr, H, Hb, N, 128, 64);
    k_gemm2<4, 0><<<gG, bG, 0, stream>>>(x, sW0, b0, sb0, S, nullptr, N, 128, 64);
    k_al<<<(N * 16 + 255) / 256, 256, 0, stream>>>(H, as0, ad0, AL, N);
    k_fused<<<gN4, 256, 0, stream>>>(Hb, AL, offs, csr, S, N);   // S <- elu(S + gat) = x1

    // ---- layer 1 (input S [N,64])
    k_gemm2<4, 2><<<gG, bG, 0, stream>>>(S, W1, nullptr, nullptr, H, Hb, N, 64, 64);
    k_gemm2<4, 0><<<gG, bG, 0, stream>>>(S, sW1, b1, sb1, T, nullptr, N, 64, 64);
    k_al<<<(N * 16 + 255) / 256, 256, 0, stream>>>(H, as1, ad1, AL, N);
    k_fused<<<gN4, 256, 0, stream>>>(Hb, AL, offs, csr, T, N);   // T <- x2

    // ---- layer 2 (input T [N,64])
    k_tobf<<<gBF, 256, 0, stream>>>(T, Tb, N * 16);
    k_wt<<<4, 256, 0, stream>>>(W2, as2, ad2, wt);
    k_w2sw<<<96, 256, 0, stream>>>(W2, w2sw);
    k_gemm2<1, 0><<<gG, bG, 0, stream>>>(T, wt, nullptr, nullptr, AL, nullptr, N, 64, 16);
    k_gemm2<3, 0><<<gG, bG, 0, stream>>>(T, sW2, b2, sb2, S, nullptr, N, 64, 40);
    k_l2f<<<(N + 15) / 16, 256, 0, stream>>>(Tb, AL, S, w2sw, offs, csr, out, N);
}

// Round 8
// 612.019 us; speedup vs baseline: 14.1966x; 1.0764x over previous
//
#include <hip/hip_runtime.h>
#include <hip/hip_bf16.h>
#include <math.h>

#define HEADS 8
#define NEG_SLOPE 0.2f

typedef __attribute__((ext_vector_type(8))) short short8v;
typedef __attribute__((ext_vector_type(4))) float f32x4;

__device__ __forceinline__ float bf2f(unsigned short u) {
    return __uint_as_float(((unsigned int)u) << 16);
}
__device__ __forceinline__ unsigned short f2bf(float f) {
    __hip_bfloat16 h = __float2bfloat16(f);
    union { __hip_bfloat16 h; unsigned short u; } c; c.h = h; return c.u;
}

// ---------------------------------------------------------------- CSR build
__global__ void k_initdeg(int* __restrict__ deg, int N) {
    int i = blockIdx.x * 256 + threadIdx.x;
    if (i < N) deg[i] = 1;  // self-loop
}

__global__ void k_count(const int* __restrict__ ei, int* __restrict__ deg, int E) {
    int i = blockIdx.x * 256 + threadIdx.x;
    if (i < E) atomicAdd(&deg[ei[E + i]], 1);  // dst row
}

__global__ void k_scan_block(const int* __restrict__ deg, int* __restrict__ offs,
                             int* __restrict__ bsum, int N) {
    __shared__ int lds[256];
    int tid = threadIdx.x;
    int base = blockIdx.x * 1024 + tid * 4;
    int v0 = (base + 0 < N) ? deg[base + 0] : 0;
    int v1 = (base + 1 < N) ? deg[base + 1] : 0;
    int v2 = (base + 2 < N) ? deg[base + 2] : 0;
    int v3 = (base + 3 < N) ? deg[base + 3] : 0;
    int t01 = v0 + v1;
    int tot = t01 + v2 + v3;
    lds[tid] = tot;
    __syncthreads();
    for (int off = 1; off < 256; off <<= 1) {
        int x = 0;
        if (tid >= off) x = lds[tid - off];
        __syncthreads();
        lds[tid] += x;
        __syncthreads();
    }
    int ex = lds[tid] - tot;
    if (tid == 255) bsum[blockIdx.x] = lds[255];
    if (base + 0 < N) offs[base + 0] = ex;
    if (base + 1 < N) offs[base + 1] = ex + v0;
    if (base + 2 < N) offs[base + 2] = ex + t01;
    if (base + 3 < N) offs[base + 3] = ex + t01 + v2;
}

__global__ void k_scan_top(int* __restrict__ bsum, int nb) {
    if (threadIdx.x == 0 && blockIdx.x == 0) {
        int run = 0;
        for (int b = 0; b < nb; ++b) { int t = bsum[b]; bsum[b] = run; run += t; }
        bsum[nb] = run;
    }
}

__global__ void k_scan_add(int* __restrict__ offs, int* __restrict__ cur,
                           const int* __restrict__ bsum, int N) {
    int i = blockIdx.x * 256 + threadIdx.x;
    if (i < N) {
        int v = offs[i] + bsum[i >> 10];
        offs[i] = v;
        cur[i] = v;
    }
    if (i == 0) offs[N] = bsum[(N + 1023) >> 10];
}

__global__ void k_scatter(const int* __restrict__ ei, int* __restrict__ cur,
                          int* __restrict__ csr, int E, int ET) {
    int i = blockIdx.x * 256 + threadIdx.x;
    if (i >= ET) return;
    int s, d;
    if (i < E) { s = ei[i]; d = ei[E + i]; }
    else       { s = d = i - E; }
    int pos = atomicAdd(&cur[d], 1);
    csr[pos] = s;
}

// ---------------------------------------------------------------- dual GEMM (+ optional AL fold)
// out_a[N,M1] = X@Wa^T  (bf16 or fp32), out_b[N,M2] = X@Wb^T + bias1 + bias2.
// AL_FOLD (requires M1==64): AL[n,j] = dot(a_j, H[n, hd*8..hd*8+8)) computed
// from the fp32 accumulators staged into LDS (reuses sW).
template <int CPT, int M1, int M2, bool AL_FOLD, bool A_BF16>
__global__ __launch_bounds__(256) void k_gemm_dual(
    const float* __restrict__ X, const float* __restrict__ Wa, const float* __restrict__ Wb,
    const float* __restrict__ bias1, const float* __restrict__ bias2,
    void* __restrict__ outa_, float* __restrict__ outb,
    const float* __restrict__ as_w, const float* __restrict__ ad_w, float* __restrict__ AL,
    int N, int K) {
    constexpr int M = M1 + M2;
    static_assert(CPT * 16 >= M, "CPT too small");
    __shared__ float sW[CPT * 16][68];
    __shared__ float sX[64][68];
    int tx = threadIdx.x, ty = threadIdx.y;
    int tid = ty * 16 + tx;
    int r0 = blockIdx.x * 64;

    float acc[4][CPT];
#pragma unroll
    for (int jc = 0; jc < CPT; ++jc) {
        int col = tx + 16 * jc;
        float b = 0.f;
        if (col >= M1 && col < M) b = bias1[col - M1] + bias2[col - M1];
#pragma unroll
        for (int jr = 0; jr < 4; ++jr) acc[jr][jc] = b;
    }

    for (int k0 = 0; k0 < K; k0 += 64) {
        __syncthreads();
        for (int idx = tid; idx < CPT * 16 * 16; idx += 256) {
            int c = idx >> 4, kq = (idx & 15) * 4;
            float4 v = make_float4(0.f, 0.f, 0.f, 0.f);
            if (c < M1) v = *(const float4*)&Wa[(size_t)c * K + k0 + kq];
            else if (c < M) v = *(const float4*)&Wb[(size_t)(c - M1) * K + k0 + kq];
            *(float4*)&sW[c][kq] = v;
        }
        for (int idx = tid; idx < 64 * 16; idx += 256) {
            int r = idx >> 4, kq = (idx & 15) * 4;
            int gr = r0 + r;
            float4 v = make_float4(0.f, 0.f, 0.f, 0.f);
            if (gr < N) v = *(const float4*)&X[(size_t)gr * K + k0 + kq];
            *(float4*)&sX[r][kq] = v;
        }
        __syncthreads();

        for (int k = 0; k < 64; k += 4) {
            float4 xr[4];
#pragma unroll
            for (int jr = 0; jr < 4; ++jr) xr[jr] = *(const float4*)&sX[ty * 4 + jr][k];
#pragma unroll
            for (int jc = 0; jc < CPT; ++jc) {
                float4 wc = *(const float4*)&sW[tx + 16 * jc][k];
#pragma unroll
                for (int jr = 0; jr < 4; ++jr)
                    acc[jr][jc] += wc.x * xr[jr].x + wc.y * xr[jr].y +
                                   wc.z * xr[jr].z + wc.w * xr[jr].w;
            }
        }
    }

#pragma unroll
    for (int jr = 0; jr < 4; ++jr) {
        int gr = r0 + ty * 4 + jr;
        if (gr >= N) continue;
#pragma unroll
        for (int jc = 0; jc < CPT; ++jc) {
            int col = tx + 16 * jc;
            if (col < M1) {
                if (A_BF16) ((unsigned short*)outa_)[(size_t)gr * M1 + col] = f2bf(acc[jr][jc]);
                else        ((float*)outa_)[(size_t)gr * M1 + col] = acc[jr][jc];
            } else if (col < M) {
                outb[(size_t)gr * M2 + (col - M1)] = acc[jr][jc];
            }
        }
    }

    if constexpr (AL_FOLD) {
        __syncthreads();                 // all reads of sW done
        float* sH = &sW[0][0];           // reuse as sH[64][68]
#pragma unroll
        for (int jr = 0; jr < 4; ++jr)
#pragma unroll
            for (int jc = 0; jc < 4; ++jc)  // cols 0..63 = H part
                sH[(ty * 4 + jr) * 68 + (tx + 16 * jc)] = acc[jr][jc];
        __syncthreads();
        int j = tid & 15, hd = j & 7;
        const float* a = (j < 8 ? as_w : ad_w) + hd * 8;
        float av[8];
#pragma unroll
        for (int c = 0; c < 8; ++c) av[c] = a[c];
#pragma unroll
        for (int q = 0; q < 4; ++q) {
            int row = (tid >> 4) + 16 * q;
            int gr = r0 + row;
            if (gr < N) {
                float sum = 0.f;
#pragma unroll
                for (int c = 0; c < 8; ++c) sum += av[c] * sH[row * 68 + hd * 8 + c];
                AL[(size_t)gr * 16 + j] = sum;
            }
        }
    }
}

// ---------------------------------------------------------------- layer-2 constant prep: wt + w2sw in one launch
// blocks 0..95: w2sw (bf16 W2T pre-swizzled for MFMA B-fragments)
// block 96: wt[j,k] = sum_c a[j][c] * W2[(hd*40+c)*64 + k]
__global__ void k_prep2(const float* __restrict__ W2, const float* __restrict__ as2,
                        const float* __restrict__ ad2, float* __restrict__ wt,
                        __hip_bfloat16* __restrict__ w2sw) {
    if (blockIdx.x < 96) {
        int t = blockIdx.x * 256 + threadIdx.x;  // < 64*48*8 = 24576
        int j = t & 7;
        int rc = t >> 3;
        int col = rc % 48, c = rc / 48;
        int k = c * 8 + j;
        int hd = k >> 6, kk = k & 63;
        float v = (col < 40) ? W2[(size_t)(hd * 40 + col) * 64 + kk] : 0.f;
        w2sw[t] = __float2bfloat16(v);
    } else {
        for (int t = threadIdx.x; t < 1024; t += 256) {
            int j = t >> 6, k = t & 63;
            int hd = j & 7;
            const float* a = (j < 8 ? as2 : ad2) + hd * 40;
            float sum = 0.f;
            for (int c = 0; c < 40; ++c) sum += a[c] * W2[(size_t)(hd * 40 + c) * 64 + k];
            wt[j * 64 + k] = sum;
        }
    }
}

// ---------------------------------------------------------------- layers 0/1: flash softmax-aggregate, bf16 rows, paired-dim layout
// 1 wave/node. Lane = es*32 + dp: edge-parity es, dim-pair dp (dims 2dp,2dp+1).
// Optional bf16 mirror output (layer 1 -> Tb for layer 2 gathers).
__global__ __launch_bounds__(256, 8) void k_fused(
    const unsigned short* __restrict__ Hb, const float* __restrict__ AL,
    const int* __restrict__ offs, const int* __restrict__ csr,
    float* __restrict__ S, unsigned short* __restrict__ Sb, int N) {
    int wid = threadIdx.x >> 6, lane = threadIdx.x & 63;
    int n = blockIdx.x * 4 + wid;
    if (n >= N) return;
    int off = offs[n], deg = offs[n + 1] - off;
    int el = lane >> 3, hd = lane & 7;
    int dp = lane & 31, es = lane >> 5;
    int hp = dp >> 2;  // head of dims (2dp,2dp+1)
    float ald = AL[(size_t)n * 16 + 8 + hd];

    bool vc = el < deg;
    int src_c = vc ? csr[off + el] : 0;
    float v_c = -1e30f;
    if (vc) { float t = AL[(size_t)src_c * 16 + hd] + ald; v_c = t > 0.f ? t : NEG_SLOPE * t; }

    float m_run = -1e30f, s_run = 0.f;
    float ax = 0.f, ay = 0.f;
    for (int b0 = 0; b0 < deg; b0 += 8) {
        unsigned int hv[4];
#pragma unroll
        for (int j = 0; j < 4; ++j) {
            int sj = __shfl(src_c, (2 * j + es) * 8);
            hv[j] = *(const unsigned int*)&Hb[(size_t)sj * 64 + 2 * dp];
        }
        int en = b0 + 8 + el;
        bool vn = en < deg;
        int src_n = vn ? csr[off + en] : 0;
        float v_n = -1e30f;
        if (vn) { float t = AL[(size_t)src_n * 16 + hd] + ald; v_n = t > 0.f ? t : NEG_SLOPE * t; }

        float mb = v_c;
#pragma unroll
        for (int d = 8; d <= 32; d <<= 1) mb = fmaxf(mb, __shfl_xor(mb, d));
        float mnew = fmaxf(m_run, mb);
        float expv = __expf(v_c - mnew);
        float sb = expv;
#pragma unroll
        for (int d = 8; d <= 32; d <<= 1) sb += __shfl_xor(sb, d);
        float f = __expf(m_run - mnew);
        s_run = s_run * f + sb;
        m_run = mnew;

        float fh = __shfl(f, hp);
        ax *= fh; ay *= fh;
#pragma unroll
        for (int j = 0; j < 4; ++j) {
            float a = __shfl(expv, (2 * j + es) * 8 + hp);
            unsigned int u = hv[j];
            ax += a * bf2f((unsigned short)(u & 0xffff));
            ay += a * bf2f((unsigned short)(u >> 16));
        }
        src_c = src_n; v_c = v_n;
    }
    float sf = __shfl(s_run, hp);
    float inv = 1.0f / (sf + 1e-16f);
    ax *= inv; ay *= inv;
    ax += __shfl_xor(ax, 32);
    ay += __shfl_xor(ay, 32);
    if (es == 0) {
        float2 sk = *(const float2*)&S[(size_t)n * 64 + 2 * dp];
        float vx = sk.x + ax, vy = sk.y + ay;
        vx = vx > 0.f ? vx : expm1f(vx);
        vy = vy > 0.f ? vy : expm1f(vy);
        *(float2*)&S[(size_t)n * 64 + 2 * dp] = make_float2(vx, vy);
        if (Sb) {
            ushort2 w;
            w.x = f2bf(vx); w.y = f2bf(vy);
            *(ushort2*)&Sb[(size_t)n * 64 + 2 * dp] = w;
        }
    }
}

// ---------------------------------------------------------------- layer 2: flash aggregate, bf16 rows, head-split layout -> bf16 LDS -> MFMA
// Lane = eh*32 + dp: head-half eh (heads 4eh..4eh+3), dim-pair dp.
__global__ __launch_bounds__(256, 8) void k_l2f(
    const unsigned short* __restrict__ Xb, const float* __restrict__ AL,
    const float* __restrict__ SK, const __hip_bfloat16* __restrict__ w2sw,
    const int* __restrict__ offs, const int* __restrict__ csr,
    float* __restrict__ out, int N) {
    __shared__ __hip_bfloat16 sA[64 * 16 * 8];  // [chunk][rot-row][8], 16 KB
    __shared__ float sC[16][48];                // 3 KB
    __shared__ float sW8[4][64];                // per-wave alpha row, 1 KB
    int wid = threadIdx.x >> 6, lane = threadIdx.x & 63;
    int el = lane >> 3, hd = lane & 7;
    int dp = lane & 31, eh = lane >> 5;

#pragma unroll 1
    for (int p = 0; p < 4; ++p) {
        int mrow = wid * 4 + p;
        int n = blockIdx.x * 16 + mrow;
        float2 acc[4];
#pragma unroll
        for (int h2 = 0; h2 < 4; ++h2) acc[h2] = make_float2(0.f, 0.f);
        if (n < N) {
            int off = offs[n], deg = offs[n + 1] - off;
            float ald = AL[(size_t)n * 16 + 8 + hd];

            bool vc = el < deg;
            int src_c = vc ? csr[off + el] : 0;
            float v_c = -1e30f;
            if (vc) { float t = AL[(size_t)src_c * 16 + hd] + ald; v_c = t > 0.f ? t : NEG_SLOPE * t; }

            float m_run = -1e30f, s_run = 0.f;
#pragma unroll 1
            for (int b0 = 0; b0 < deg; b0 += 8) {
                unsigned int xv0[4];
#pragma unroll
                for (int j = 0; j < 4; ++j) {
                    int sj = __shfl(src_c, j * 8);
                    xv0[j] = *(const unsigned int*)&Xb[(size_t)sj * 64 + 2 * dp];
                }
                int en = b0 + 8 + el;
                bool vn = en < deg;
                int src_n = vn ? csr[off + en] : 0;
                float v_n = -1e30f;
                if (vn) { float t = AL[(size_t)src_n * 16 + hd] + ald; v_n = t > 0.f ? t : NEG_SLOPE * t; }

                float mb = v_c;
#pragma unroll
                for (int d = 8; d <= 32; d <<= 1) mb = fmaxf(mb, __shfl_xor(mb, d));
                float mnew = fmaxf(m_run, mb);
                float expv = __expf(v_c - mnew);
                float sb = expv;
#pragma unroll
                for (int d = 8; d <= 32; d <<= 1) sb += __shfl_xor(sb, d);
                float f = __expf(m_run - mnew);
                s_run = s_run * f + sb;
                m_run = mnew;

                sW8[wid][lane] = expv;  // stats layout [e&7]*8+hd, same-wave consume
#pragma unroll
                for (int h2 = 0; h2 < 4; ++h2) {
                    float ff = __shfl(f, 4 * eh + h2);
                    acc[h2].x *= ff; acc[h2].y *= ff;
                }
#pragma unroll
                for (int j = 0; j < 4; ++j) {
                    float4 a4 = *(const float4*)&sW8[wid][j * 8 + 4 * eh];
                    float hx = bf2f((unsigned short)(xv0[j] & 0xffff));
                    float hy = bf2f((unsigned short)(xv0[j] >> 16));
                    acc[0].x += a4.x * hx; acc[0].y += a4.x * hy;
                    acc[1].x += a4.y * hx; acc[1].y += a4.y * hy;
                    acc[2].x += a4.z * hx; acc[2].y += a4.z * hy;
                    acc[3].x += a4.w * hx; acc[3].y += a4.w * hy;
                }
#pragma unroll
                for (int j = 0; j < 4; ++j) {
                    int sj = __shfl(src_c, (j + 4) * 8);
                    xv0[j] = *(const unsigned int*)&Xb[(size_t)sj * 64 + 2 * dp];
                }
#pragma unroll
                for (int j = 0; j < 4; ++j) {
                    float4 a4 = *(const float4*)&sW8[wid][(j + 4) * 8 + 4 * eh];
                    float hx = bf2f((unsigned short)(xv0[j] & 0xffff));
                    float hy = bf2f((unsigned short)(xv0[j] >> 16));
                    acc[0].x += a4.x * hx; acc[0].y += a4.x * hy;
                    acc[1].x += a4.y * hx; acc[1].y += a4.y * hy;
                    acc[2].x += a4.z * hx; acc[2].y += a4.z * hy;
                    acc[3].x += a4.w * hx; acc[3].y += a4.w * hy;
                }
                src_c = src_n; v_c = v_n;
            }
#pragma unroll
            for (int h2 = 0; h2 < 4; ++h2) {
                float sv = __shfl(s_run, 4 * eh + h2);
                float iv = 1.0f / (sv + 1e-16f);
                acc[h2].x *= iv; acc[h2].y *= iv;
            }
        }
#pragma unroll
        for (int h2 = 0; h2 < 4; ++h2) {
            int K0 = (4 * eh + h2) * 64 + 2 * dp;
            int chunk = K0 >> 3, pos = K0 & 7;
            ushort2 w;
            w.x = f2bf(acc[h2].x); w.y = f2bf(acc[h2].y);
            *(ushort2*)&sA[chunk * 128 + ((mrow + chunk) & 15) * 8 + pos] = w;
        }
    }
    __syncthreads();

    // ---- MFMA projection: waves 0..2 each one 16-col N-tile, K=512
    if (wid < 3) {
        f32x4 cacc = {0.f, 0.f, 0.f, 0.f};
        int grp = lane >> 4;
        int r16 = lane & 15;
#pragma unroll 4
        for (int ks = 0; ks < 16; ++ks) {
            int c = ks * 4 + grp;
            short8v av = *(const short8v*)&sA[c * 128 + ((r16 + c) & 15) * 8];
            short8v bv = *(const short8v*)&w2sw[(size_t)(c * 48 + wid * 16 + r16) * 8];
            cacc = __builtin_amdgcn_mfma_f32_16x16x32_bf16(av, bv, cacc, 0, 0, 0);
        }
#pragma unroll
        for (int jj = 0; jj < 4; ++jj)
            sC[grp * 4 + jj][wid * 16 + r16] = cacc[jj];
    }
    __syncthreads();

    // ---- epilogue: + skip, log_softmax over 40 outputs
    for (int p = 0; p < 4; ++p) {
        int mrow = wid * 4 + p;
        int n = blockIdx.x * 16 + mrow;
        if (n >= N) continue;
        float val = (lane < 40) ? SK[(size_t)n * 40 + lane] + sC[mrow][lane] * 0.125f : -INFINITY;
        float mx = val;
#pragma unroll
        for (int d = 32; d; d >>= 1) mx = fmaxf(mx, __shfl_xor(mx, d));
        float ex = (lane < 40) ? __expf(val - mx) : 0.f;
        float sm = ex;
#pragma unroll
        for (int d = 32; d; d >>= 1) sm += __shfl_xor(sm, d);
        if (lane < 40) out[(size_t)n * 40 + lane] = val - mx - logf(sm);
    }
}

// ---------------------------------------------------------------- launch
extern "C" void kernel_launch(void* const* d_in, const int* in_sizes, int n_in,
                              void* d_out, int out_size, void* d_ws, size_t ws_size,
                              hipStream_t stream) {
    const float* x   = (const float*)d_in[0];
    const int*   ei  = (const int*)d_in[1];
    const float* W0  = (const float*)d_in[2];
    const float* as0 = (const float*)d_in[3];
    const float* ad0 = (const float*)d_in[4];
    const float* b0  = (const float*)d_in[5];
    const float* sW0 = (const float*)d_in[6];
    const float* sb0 = (const float*)d_in[7];
    const float* W1  = (const float*)d_in[8];
    const float* as1 = (const float*)d_in[9];
    const float* ad1 = (const float*)d_in[10];
    const float* b1  = (const float*)d_in[11];
    const float* sW1 = (const float*)d_in[12];
    const float* sb1 = (const float*)d_in[13];
    const float* W2  = (const float*)d_in[14];
    const float* as2 = (const float*)d_in[15];
    const float* ad2 = (const float*)d_in[16];
    const float* b2  = (const float*)d_in[17];
    const float* sW2 = (const float*)d_in[18];
    const float* sb2 = (const float*)d_in[19];
    float* out = (float*)d_out;

    int N = in_sizes[0] / 128;
    int E = in_sizes[1] / 2;
    int ET = E + N;

    char* wsp = (char*)d_ws;
    size_t woff = 0;
    auto A = [&](size_t nbytes) -> void* {
        void* p = wsp + woff;
        woff = (woff + nbytes + 255) & ~(size_t)255;
        return p;
    };
    int* offs   = (int*)A((size_t)(N + 1) * 4);
    int* cur    = (int*)A((size_t)N * 4);
    int* deg    = (int*)A((size_t)N * 4);
    int* bsum   = (int*)A(4096);
    int* csr    = (int*)A((size_t)ET * 4);
    float* wt   = (float*)A(1024 * 4);
    __hip_bfloat16* w2sw = (__hip_bfloat16*)A(64 * 48 * 8 * 2);
    float* AL   = (float*)A((size_t)N * 16 * 4);
    float* S    = (float*)A((size_t)N * 64 * 4);
    float* T    = (float*)A((size_t)N * 64 * 4);
    unsigned short* Hb = (unsigned short*)A((size_t)N * 64 * 2);
    unsigned short* Tb = (unsigned short*)A((size_t)N * 64 * 2);
    (void)ws_size; (void)n_in; (void)out_size;

    // ---- CSR build (6 launches)
    k_initdeg<<<(N + 255) / 256, 256, 0, stream>>>(deg, N);
    k_count<<<(E + 255) / 256, 256, 0, stream>>>(ei, deg, E);
    int nb = (N + 1023) / 1024;
    k_scan_block<<<nb, 256, 0, stream>>>(deg, offs, bsum, N);
    k_scan_top<<<1, 1, 0, stream>>>(bsum, nb);
    k_scan_add<<<(N + 255) / 256, 256, 0, stream>>>(offs, cur, bsum, N);
    k_scatter<<<(ET + 255) / 256, 256, 0, stream>>>(ei, cur, csr, E, ET);

    // ---- layer-2 constants (independent)
    k_prep2<<<97, 256, 0, stream>>>(W2, as2, ad2, wt, w2sw);

    dim3 bG(16, 16);
    int gG = (N + 63) / 64;
    int gN4 = (N + 3) / 4;

    // ---- layer 0 (input x [N,128]): Hb + S(skip+biases) + AL in one GEMM
    k_gemm_dual<8, 64, 64, true, true><<<gG, bG, 0, stream>>>(
        x, W0, sW0, b0, sb0, Hb, S, as0, ad0, AL, N, 128);
    k_fused<<<gN4, 256, 0, stream>>>(Hb, AL, offs, csr, S, nullptr, N);  // S <- x1

    // ---- layer 1 (input S [N,64])
    k_gemm_dual<8, 64, 64, true, true><<<gG, bG, 0, stream>>>(
        S, W1, sW1, b1, sb1, Hb, T, as1, ad1, AL, N, 64);
    k_fused<<<gN4, 256, 0, stream>>>(Hb, AL, offs, csr, T, Tb, N);       // T <- x2 (+bf16 Tb)

    // ---- layer 2 (input T [N,64]): AL(wt part) + S(skip) in one GEMM
    k_gemm_dual<4, 16, 40, false, false><<<gG, bG, 0, stream>>>(
        T, wt, sW2, b2, sb2, AL, S, nullptr, nullptr, nullptr, N, 64);
    k_l2f<<<(N + 15) / 16, 256, 0, stream>>>(Tb, AL, S, w2sw, offs, csr, out, N);
}